// Round 1
// baseline (3936.694 us; speedup 1.0000x reference)
//
#include <hip/hip_runtime.h>
#include <hip/hip_bf16.h>
#include <math.h>

#define N_NODES 50000
#define N_EDGES 800000
#define F_IN 256
#define HID 32
#define HEADS 4
#define HC 128            // HID*HEADS
#define CLASSES 40
#define LAYERS 2
#define SLOPE 0.1f
#define EE (N_EDGES + N_NODES)   // edges + self loops

// ---------- order-preserving float<->uint for atomicMax on floats ----------
__device__ __forceinline__ unsigned fenc(float f) {
    unsigned u = __float_as_uint(f);
    return (u & 0x80000000u) ? ~u : (u | 0x80000000u);
}
__device__ __forceinline__ float fdec(unsigned u) {
    return (u & 0x80000000u) ? __uint_as_float(u & 0x7fffffffu)
                             : __uint_as_float(~u);
}

// ---------- generic tiled fp32 GEMM: C[M,N] = A[M,K] @ B[K,N] ----------
#define TS 16
__global__ void gemm16(const float* __restrict__ A, const float* __restrict__ B,
                       float* __restrict__ C, int M, int N, int K) {
    __shared__ float As[TS][TS];
    __shared__ float Bs[TS][TS + 1];
    int tx = threadIdx.x, ty = threadIdx.y;
    int row = blockIdx.y * TS + ty;
    int col = blockIdx.x * TS + tx;
    float acc = 0.f;
    for (int k0 = 0; k0 < K; k0 += TS) {
        As[ty][tx] = (row < M && (k0 + tx) < K) ? A[(size_t)row * K + k0 + tx] : 0.f;
        Bs[ty][tx] = ((k0 + ty) < K && col < N) ? B[(size_t)(k0 + ty) * N + col] : 0.f;
        __syncthreads();
#pragma unroll
        for (int k = 0; k < TS; ++k) acc += As[ty][k] * Bs[k][tx];
        __syncthreads();
    }
    if (row < M && col < N) C[(size_t)row * N + col] = acc;
}

// ---------- per-node attention coefficients ----------
// alpha_src[n,h] = dot(hp[n, h*HID : (h+1)*HID], att[h, 0:HID])
// alpha_dst[n,h] = dot(hp[n, h*HID : (h+1)*HID], att[h, HID:2*HID])
__global__ void node_alpha(const float* __restrict__ hp, const float* __restrict__ att,
                           float* __restrict__ asrc, float* __restrict__ adst) {
    int t = blockIdx.x * blockDim.x + threadIdx.x;  // n*HEADS + h
    if (t >= N_NODES * HEADS) return;
    int n = t >> 2, h = t & 3;
    const float* v = hp + (size_t)n * HC + h * HID;
    const float* as = att + h * 2 * HID;
    const float* ad = as + HID;
    float s = 0.f, d = 0.f;
#pragma unroll
    for (int c = 0; c < HID; ++c) { float x = v[c]; s = fmaf(x, as[c], s); d = fmaf(x, ad[c], d); }
    asrc[t] = s;
    adst[t] = d;
}

// ---------- edge pass 1: logits + segment max ----------
__global__ void edge_logit_max(const int* __restrict__ ei,
                               const float* __restrict__ asrc, const float* __restrict__ adst,
                               float* __restrict__ elog, unsigned* __restrict__ mmax) {
    int e = blockIdx.x * blockDim.x + threadIdx.x;
    if (e >= EE) return;
    int s, d;
    if (e < N_EDGES) { s = ei[e]; d = ei[N_EDGES + e]; } else { s = d = e - N_EDGES; }
    float4 a = *(const float4*)(asrc + (size_t)s * 4);
    float4 b = *(const float4*)(adst + (size_t)d * 4);
    float4 l;
    l.x = a.x + b.x; l.x = l.x > 0.f ? l.x : SLOPE * l.x;
    l.y = a.y + b.y; l.y = l.y > 0.f ? l.y : SLOPE * l.y;
    l.z = a.z + b.z; l.z = l.z > 0.f ? l.z : SLOPE * l.z;
    l.w = a.w + b.w; l.w = l.w > 0.f ? l.w : SLOPE * l.w;
    *(float4*)(elog + (size_t)e * 4) = l;
    unsigned* m = mmax + (size_t)d * 4;
    atomicMax(m + 0, fenc(l.x));
    atomicMax(m + 1, fenc(l.y));
    atomicMax(m + 2, fenc(l.z));
    atomicMax(m + 3, fenc(l.w));
}

// ---------- edge pass 2: e = exp(logit - m[dst]); z[dst] += e ----------
__global__ void edge_expsum(const int* __restrict__ ei, float* __restrict__ elog,
                            const unsigned* __restrict__ mmax, float* __restrict__ z) {
    int e = blockIdx.x * blockDim.x + threadIdx.x;
    if (e >= EE) return;
    int d;
    if (e < N_EDGES) { d = ei[N_EDGES + e]; } else { d = e - N_EDGES; }
    float4 l = *(float4*)(elog + (size_t)e * 4);
    uint4 mu = *(const uint4*)(mmax + (size_t)d * 4);
    float4 ex;
    ex.x = expf(l.x - fdec(mu.x));
    ex.y = expf(l.y - fdec(mu.y));
    ex.z = expf(l.z - fdec(mu.z));
    ex.w = expf(l.w - fdec(mu.w));
    *(float4*)(elog + (size_t)e * 4) = ex;
    float* zp = z + (size_t)d * 4;
    atomicAdd(zp + 0, ex.x);
    atomicAdd(zp + 1, ex.y);
    atomicAdd(zp + 2, ex.z);
    atomicAdd(zp + 3, ex.w);
}

// ---------- edge pass 3: out[dst] += hp[src] * alpha ----------
// one thread per (edge, 4-channel group); 32 groups cover HC=128
__global__ void edge_msg(const int* __restrict__ ei, const float* __restrict__ elog,
                         const float* __restrict__ z, const float* __restrict__ hp,
                         float* __restrict__ outacc) {
    int gid = blockIdx.x * blockDim.x + threadIdx.x;
    int e = gid >> 5;
    if (e >= EE) return;
    int q = gid & 31;        // channel group: channels q*4 .. q*4+3
    int head = q >> 3;       // 8 groups per head
    int s, d;
    if (e < N_EDGES) { s = ei[e]; d = ei[N_EDGES + e]; } else { s = d = e - N_EDGES; }
    float ev = elog[(size_t)e * 4 + head];
    float zv = z[(size_t)d * 4 + head];
    float alpha = ev / zv;
    float4 hv = *(const float4*)(hp + (size_t)s * HC + q * 4);
    float* o = outacc + (size_t)d * HC + q * 4;
    atomicAdd(o + 0, hv.x * alpha);
    atomicAdd(o + 1, hv.y * alpha);
    atomicAdd(o + 2, hv.z * alpha);
    atomicAdd(o + 3, hv.w * alpha);
}

// ---------- bias + ELU (in place) ----------
__global__ void bias_elu(float* __restrict__ acc, const float* __restrict__ bias, int n) {
    int i = blockIdx.x * blockDim.x + threadIdx.x;
    if (i >= n) return;
    float v = acc[i] + bias[i & (HC - 1)];
    acc[i] = v > 0.f ? v : expm1f(v);
}

// ---------- fused classifier GEMM + log_softmax: one wave (64) per row ----------
__global__ void cls_logsoftmax(const float* __restrict__ h, const float* __restrict__ Wout,
                               float* __restrict__ out) {
    int row = blockIdx.x;
    __shared__ float hs[HC];
    int t = threadIdx.x;  // 64 threads = 1 wave
    hs[t] = h[(size_t)row * HC + t];
    hs[t + 64] = h[(size_t)row * HC + 64 + t];
    __syncthreads();
    float acc = 0.f;
    if (t < CLASSES) {
#pragma unroll
        for (int k = 0; k < HC; ++k) acc = fmaf(hs[k], Wout[k * CLASSES + t], acc);
    }
    float v = (t < CLASSES) ? acc : -1e30f;
#pragma unroll
    for (int off = 32; off; off >>= 1) v = fmaxf(v, __shfl_xor(v, off));
    float m = v;
    float ex = (t < CLASSES) ? expf(acc - m) : 0.f;
#pragma unroll
    for (int off = 32; off; off >>= 1) ex += __shfl_xor(ex, off);
    float ls = logf(ex);
    if (t < CLASSES) out[(size_t)row * CLASSES + t] = acc - m - ls;
}

extern "C" void kernel_launch(void* const* d_in, const int* in_sizes, int n_in,
                              void* d_out, int out_size, void* d_ws, size_t ws_size,
                              hipStream_t stream) {
    const float* x      = (const float*)d_in[0];
    const int*   ei     = (const int*)d_in[1];
    const float* w_in   = (const float*)d_in[2];
    const float* Ws     = (const float*)d_in[3];
    const float* atts   = (const float*)d_in[4];
    const float* biases = (const float*)d_in[5];
    const float* w_out  = (const float*)d_in[6];
    float* out = (float*)d_out;

    // workspace partition
    char* wp = (char*)d_ws;
    float* h   = (float*)wp; wp += (size_t)N_NODES * HC * 4;
    float* h2  = (float*)wp; wp += (size_t)N_NODES * HC * 4;
    float* hp  = (float*)wp; wp += (size_t)N_NODES * HC * 4;
    float* asrc = (float*)wp; wp += (size_t)N_NODES * HEADS * 4;
    float* adst = (float*)wp; wp += (size_t)N_NODES * HEADS * 4;
    unsigned* mm = (unsigned*)wp; wp += (size_t)N_NODES * HEADS * 4;
    float* z    = (float*)wp; wp += (size_t)N_NODES * HEADS * 4;
    float* elog = (float*)wp; wp += (size_t)EE * HEADS * 4;

    dim3 b16(TS, TS);

    // h = x @ w_in   (N x F_IN) @ (F_IN x HC)
    gemm16<<<dim3(HC / TS, (N_NODES + TS - 1) / TS), b16, 0, stream>>>(x, w_in, h, N_NODES, HC, F_IN);

    float* hin = h;
    float* hout = h2;
    for (int l = 0; l < LAYERS; ++l) {
        // hp = hin @ W[l]
        gemm16<<<dim3(HC / TS, (N_NODES + TS - 1) / TS), b16, 0, stream>>>(
            hin, Ws + (size_t)l * HC * HC, hp, N_NODES, HC, HC);
        // per-node attention dots
        node_alpha<<<(N_NODES * HEADS + 255) / 256, 256, 0, stream>>>(
            hp, atts + (size_t)l * HEADS * 2 * HID, asrc, adst);
        // init segment buffers
        hipMemsetAsync(mm, 0, (size_t)N_NODES * HEADS * 4, stream);   // encoded -inf
        hipMemsetAsync(z, 0, (size_t)N_NODES * HEADS * 4, stream);
        hipMemsetAsync(hout, 0, (size_t)N_NODES * HC * 4, stream);
        // edge passes
        edge_logit_max<<<(EE + 255) / 256, 256, 0, stream>>>(ei, asrc, adst, elog, mm);
        edge_expsum<<<(EE + 255) / 256, 256, 0, stream>>>(ei, elog, mm, z);
        edge_msg<<<((size_t)EE * 32 + 255) / 256, 256, 0, stream>>>(ei, elog, z, hp, hout);
        // bias + elu
        bias_elu<<<(N_NODES * HC + 255) / 256, 256, 0, stream>>>(
            hout, biases + (size_t)l * HC, N_NODES * HC);
        // swap
        float* tmp = hin; hin = hout; hout = tmp;
    }

    // classifier + log_softmax
    cls_logsoftmax<<<N_NODES, 64, 0, stream>>>(hin, w_out, out);
}

// Round 2
// 734.236 us; speedup vs baseline: 5.3616x; 5.3616x over previous
//
#include <hip/hip_runtime.h>
#include <hip/hip_bf16.h>
#include <math.h>

#define N_NODES 50000
#define N_EDGES 800000
#define F_IN 256
#define HID 32
#define HEADS 4
#define HC 128            // HID*HEADS
#define CLASSES 40
#define LAYERS 2
#define SLOPE 0.1f
#define EE (N_EDGES + N_NODES)   // edges + self loops

// ---------- generic tiled fp32 GEMM: C[M,N] = A[M,K] @ B[K,N] ----------
#define TS 16
__global__ void gemm16(const float* __restrict__ A, const float* __restrict__ B,
                       float* __restrict__ C, int M, int N, int K) {
    __shared__ float As[TS][TS];
    __shared__ float Bs[TS][TS + 1];
    int tx = threadIdx.x, ty = threadIdx.y;
    int row = blockIdx.y * TS + ty;
    int col = blockIdx.x * TS + tx;
    float acc = 0.f;
    for (int k0 = 0; k0 < K; k0 += TS) {
        As[ty][tx] = (row < M && (k0 + tx) < K) ? A[(size_t)row * K + k0 + tx] : 0.f;
        Bs[ty][tx] = ((k0 + ty) < K && col < N) ? B[(size_t)(k0 + ty) * N + col] : 0.f;
        __syncthreads();
#pragma unroll
        for (int k = 0; k < TS; ++k) acc += As[ty][k] * Bs[k][tx];
        __syncthreads();
    }
    if (row < M && col < N) C[(size_t)row * N + col] = acc;
}

// ---------- per-node attention coefficients ----------
__global__ void node_alpha(const float* __restrict__ hp, const float* __restrict__ att,
                           float* __restrict__ asrc, float* __restrict__ adst) {
    int t = blockIdx.x * blockDim.x + threadIdx.x;  // n*HEADS + h
    if (t >= N_NODES * HEADS) return;
    int n = t >> 2, h = t & 3;
    const float* v = hp + (size_t)n * HC + h * HID;
    const float* as = att + h * 2 * HID;
    const float* ad = as + HID;
    float s = 0.f, d = 0.f;
#pragma unroll
    for (int c = 0; c < HID; ++c) { float x = v[c]; s = fmaf(x, as[c], s); d = fmaf(x, ad[c], d); }
    asrc[t] = s;
    adst[t] = d;
}

// ---------- CSR build ----------
__global__ void edge_hist(const int* __restrict__ ei, int* __restrict__ cnt) {
    int e = blockIdx.x * blockDim.x + threadIdx.x;
    if (e >= EE) return;
    int d = (e < N_EDGES) ? ei[N_EDGES + e] : (e - N_EDGES);
    atomicAdd(&cnt[d], 1);
}

// single-block scan over 50000 counts -> rowptr (exclusive) + cursor copy
__global__ void prefix50k(const int* __restrict__ cnt, int* __restrict__ rowptr,
                          int* __restrict__ cursor) {
    __shared__ int wsum[17];
    __shared__ int carry_s;
    int t = threadIdx.x, lane = t & 63, w = t >> 6;
    if (t == 0) carry_s = 0;
    __syncthreads();
    for (int base = 0; base < N_NODES; base += 1024) {
        int i = base + t;
        int v = (i < N_NODES) ? cnt[i] : 0;
        // inclusive wave scan
        int x = v;
#pragma unroll
        for (int off = 1; off < 64; off <<= 1) {
            int y = __shfl_up(x, off);
            if (lane >= off) x += y;
        }
        if (lane == 63) wsum[w] = x;
        __syncthreads();
        if (t == 0) {
            int run = 0;
#pragma unroll
            for (int k = 0; k < 16; ++k) { int tmp = wsum[k]; wsum[k] = run; run += tmp; }
            wsum[16] = run;
        }
        __syncthreads();
        int excl = carry_s + wsum[w] + x - v;
        if (i < N_NODES) { rowptr[i] = excl; cursor[i] = excl; }
        __syncthreads();
        if (t == 0) carry_s += wsum[16];
        __syncthreads();
    }
    if (t == 0) rowptr[N_NODES] = carry_s;
}

__global__ void edge_scatter(const int* __restrict__ ei, int* __restrict__ cursor,
                             int* __restrict__ ssrc) {
    int e = blockIdx.x * blockDim.x + threadIdx.x;
    if (e >= EE) return;
    int s, d;
    if (e < N_EDGES) { s = ei[e]; d = ei[N_EDGES + e]; } else { s = d = e - N_EDGES; }
    int pos = atomicAdd(&cursor[d], 1);
    ssrc[pos] = s;
}

// ---------- fused per-node GAT aggregate: softmax over in-edges + weighted gather ----------
__device__ __forceinline__ float lrelu(float v) { return v > 0.f ? v : SLOPE * v; }
__device__ __forceinline__ void onl(float l, float& m, float& s) {
    if (l > m) { s = s * expf(m - l) + 1.f; m = l; }
    else       { s += expf(l - m); }
}

#define WPB 4   // waves (nodes) per block
__global__ __launch_bounds__(256) void gat_gather(
    const int* __restrict__ rowptr, const int* __restrict__ ssrc,
    const float* __restrict__ asrc, const float* __restrict__ adst,
    const float* __restrict__ hp, const float* __restrict__ bias,
    float* __restrict__ hout)
{
    __shared__ float s_exp[WPB][64][4];
    __shared__ int   s_src[WPB][64];
    int w = threadIdx.x >> 6;
    int lane = threadIdx.x & 63;
    int node = blockIdx.x * WPB + w;
    if (node >= N_NODES) return;
    int beg = rowptr[node];
    int deg = rowptr[node + 1] - beg;
    float4 ad = *(const float4*)(adst + (size_t)node * 4);

    // ---- phase A: per-lane online softmax stats over strided edges ----
    float4 m = make_float4(-1e30f, -1e30f, -1e30f, -1e30f);
    float4 z = make_float4(0.f, 0.f, 0.f, 0.f);
    for (int i = lane; i < deg; i += 64) {
        int s = ssrc[beg + i];
        float4 a = *(const float4*)(asrc + (size_t)s * 4);
        onl(lrelu(a.x + ad.x), m.x, z.x);
        onl(lrelu(a.y + ad.y), m.y, z.y);
        onl(lrelu(a.z + ad.z), m.z, z.z);
        onl(lrelu(a.w + ad.w), m.w, z.w);
    }
    // ---- butterfly merge across 64 lanes ----
#pragma unroll
    for (int off = 1; off < 64; off <<= 1) {
        float4 mo, zo;
        mo.x = __shfl_xor(m.x, off); zo.x = __shfl_xor(z.x, off);
        mo.y = __shfl_xor(m.y, off); zo.y = __shfl_xor(z.y, off);
        mo.z = __shfl_xor(m.z, off); zo.z = __shfl_xor(z.z, off);
        mo.w = __shfl_xor(m.w, off); zo.w = __shfl_xor(z.w, off);
        float nm;
        nm = fmaxf(m.x, mo.x); z.x = z.x * expf(m.x - nm) + zo.x * expf(mo.x - nm); m.x = nm;
        nm = fmaxf(m.y, mo.y); z.y = z.y * expf(m.y - nm) + zo.y * expf(mo.y - nm); m.y = nm;
        nm = fmaxf(m.z, mo.z); z.z = z.z * expf(m.z - nm) + zo.z * expf(mo.z - nm); m.z = nm;
        nm = fmaxf(m.w, mo.w); z.w = z.w * expf(m.w - nm) + zo.w * expf(mo.w - nm); m.w = nm;
    }
    int head = lane >> 4;   // lane owns channels {2*lane, 2*lane+1}; head = (2*lane)/32
    float mh = (head == 0) ? m.x : (head == 1) ? m.y : (head == 2) ? m.z : m.w;
    float zh = (head == 0) ? z.x : (head == 1) ? z.y : (head == 2) ? z.z : z.w;
    float zinv = 1.f / zh;

    // ---- phase C: channel-parallel weighted gather, 64-edge chunks via LDS ----
    float acc0 = 0.f, acc1 = 0.f;
    for (int c0 = 0; c0 < deg; c0 += 64) {
        int n_ch = min(64, deg - c0);
        if (lane < n_ch) {
            int s = ssrc[beg + c0 + lane];
            float4 a = *(const float4*)(asrc + (size_t)s * 4);
            float4 ex;
            ex.x = expf(lrelu(a.x + ad.x) - m.x);
            ex.y = expf(lrelu(a.y + ad.y) - m.y);
            ex.z = expf(lrelu(a.z + ad.z) - m.z);
            ex.w = expf(lrelu(a.w + ad.w) - m.w);
            *(float4*)&s_exp[w][lane][0] = ex;
            s_src[w][lane] = s;
        }
        asm volatile("s_waitcnt lgkmcnt(0)" ::: "memory");   // same-wave LDS visibility
#pragma unroll 4
        for (int i = 0; i < n_ch; ++i) {
            float e = s_exp[w][i][head];
            int s = s_src[w][i];
            float alpha = e * zinv;
            float2 hv = *(const float2*)(hp + (size_t)s * HC + lane * 2);
            acc0 = fmaf(hv.x, alpha, acc0);
            acc1 = fmaf(hv.y, alpha, acc1);
        }
    }

    // ---- fused bias + ELU + store ----
    float b0 = bias[lane * 2], b1 = bias[lane * 2 + 1];
    float v0 = acc0 + b0; v0 = v0 > 0.f ? v0 : expm1f(v0);
    float v1 = acc1 + b1; v1 = v1 > 0.f ? v1 : expm1f(v1);
    *(float2*)(hout + (size_t)node * HC + lane * 2) = make_float2(v0, v1);
}

// ---------- fused classifier GEMM + log_softmax: one wave per row ----------
__global__ void cls_logsoftmax(const float* __restrict__ h, const float* __restrict__ Wout,
                               float* __restrict__ out) {
    int row = blockIdx.x;
    __shared__ float hs[HC];
    int t = threadIdx.x;  // 64 threads = 1 wave
    hs[t] = h[(size_t)row * HC + t];
    hs[t + 64] = h[(size_t)row * HC + 64 + t];
    __syncthreads();
    float acc = 0.f;
    if (t < CLASSES) {
#pragma unroll
        for (int k = 0; k < HC; ++k) acc = fmaf(hs[k], Wout[k * CLASSES + t], acc);
    }
    float v = (t < CLASSES) ? acc : -1e30f;
#pragma unroll
    for (int off = 32; off; off >>= 1) v = fmaxf(v, __shfl_xor(v, off));
    float m = v;
    float ex = (t < CLASSES) ? expf(acc - m) : 0.f;
#pragma unroll
    for (int off = 32; off; off >>= 1) ex += __shfl_xor(ex, off);
    float ls = logf(ex);
    if (t < CLASSES) out[(size_t)row * CLASSES + t] = acc - m - ls;
}

extern "C" void kernel_launch(void* const* d_in, const int* in_sizes, int n_in,
                              void* d_out, int out_size, void* d_ws, size_t ws_size,
                              hipStream_t stream) {
    const float* x      = (const float*)d_in[0];
    const int*   ei     = (const int*)d_in[1];
    const float* w_in   = (const float*)d_in[2];
    const float* Ws     = (const float*)d_in[3];
    const float* atts   = (const float*)d_in[4];
    const float* biases = (const float*)d_in[5];
    const float* w_out  = (const float*)d_in[6];
    float* out = (float*)d_out;

    // workspace partition (16B-aligned blocks)
    char* wp = (char*)d_ws;
    float* h    = (float*)wp; wp += (size_t)N_NODES * HC * 4;
    float* h2   = (float*)wp; wp += (size_t)N_NODES * HC * 4;
    float* hp   = (float*)wp; wp += (size_t)N_NODES * HC * 4;
    float* asrc = (float*)wp; wp += (size_t)N_NODES * HEADS * 4;
    float* adst = (float*)wp; wp += (size_t)N_NODES * HEADS * 4;
    int* cnt    = (int*)wp;   wp += (size_t)N_NODES * 4;
    int* rowptr = (int*)wp;   wp += (size_t)(N_NODES + 4) * 4;
    int* cursor = (int*)wp;   wp += (size_t)N_NODES * 4;
    int* ssrc   = (int*)wp;   wp += (size_t)EE * 4;

    dim3 b16(TS, TS);

    // ---- CSR build (once per call; shared by both layers) ----
    hipMemsetAsync(cnt, 0, (size_t)N_NODES * 4, stream);
    edge_hist<<<(EE + 255) / 256, 256, 0, stream>>>(ei, cnt);
    prefix50k<<<1, 1024, 0, stream>>>(cnt, rowptr, cursor);
    edge_scatter<<<(EE + 255) / 256, 256, 0, stream>>>(ei, cursor, ssrc);

    // h = x @ w_in
    gemm16<<<dim3(HC / TS, (N_NODES + TS - 1) / TS), b16, 0, stream>>>(x, w_in, h, N_NODES, HC, F_IN);

    float* hin = h;
    float* hout = h2;
    for (int l = 0; l < LAYERS; ++l) {
        gemm16<<<dim3(HC / TS, (N_NODES + TS - 1) / TS), b16, 0, stream>>>(
            hin, Ws + (size_t)l * HC * HC, hp, N_NODES, HC, HC);
        node_alpha<<<(N_NODES * HEADS + 255) / 256, 256, 0, stream>>>(
            hp, atts + (size_t)l * HEADS * 2 * HID, asrc, adst);
        gat_gather<<<(N_NODES + WPB - 1) / WPB, 64 * WPB, 0, stream>>>(
            rowptr, ssrc, asrc, adst, hp, biases + (size_t)l * HC, hout);
        float* tmp = hin; hin = hout; hout = tmp;
    }

    cls_logsoftmax<<<N_NODES, 64, 0, stream>>>(hin, w_out, out);
}

// Round 3
// 484.439 us; speedup vs baseline: 8.1263x; 1.5156x over previous
//
#include <hip/hip_runtime.h>
#include <hip/hip_bf16.h>
#include <math.h>

#define N_NODES 50000
#define N_EDGES 800000
#define F_IN 256
#define HID 32
#define HEADS 4
#define HC 128            // HID*HEADS
#define CLASSES 40
#define LAYERS 2
#define SLOPE 0.1f
#define EE (N_EDGES + N_NODES)   // edges + self loops

// ---------- register-blocked fp32 GEMM, N fixed at 128 ----------
// C[M,128] = A[M,K] @ B[K,128].  Block: 256 threads -> 64x128 tile,
// thread computes 8 rows x 4 cols. A staged transposed (As[k][m]) so the
// 8-row fragment is 2x ds_read_b128 broadcast; B tile read as b128.
#define BM 64
#define BN 128
#define BK 16
#define AS_LD 68   // stride 68 floats = 272 B: 16B-aligned rows, 2-way-bank only
__global__ __launch_bounds__(256) void gemm_rb(const float* __restrict__ A,
                                               const float* __restrict__ B,
                                               float* __restrict__ C, int M, int K) {
    __shared__ float As[BK * AS_LD];
    __shared__ float Bs[BK][BN];
    int t = threadIdx.x;
    int tx = t & 31;          // col group: cols tx*4 .. tx*4+3
    int ty = t >> 5;          // row group: rows ty*8 .. ty*8+7
    int row0 = blockIdx.x * BM;
    float acc[8][4] = {};
    // A-load mapping: thread t loads float4 at (row0 + t/4, k0 + (t&3)*4)
    int ar = t >> 2;
    int ak = (t & 3) * 4;
    // B-load mapping: rows t>>5 and (t>>5)+8, col (t&31)*4
    int br = t >> 5;
    int bc = (t & 31) * 4;
    for (int k0 = 0; k0 < K; k0 += BK) {
        float4 av = (row0 + ar < M) ? *(const float4*)(A + (size_t)(row0 + ar) * K + k0 + ak)
                                    : make_float4(0.f, 0.f, 0.f, 0.f);
        As[(ak + 0) * AS_LD + ar] = av.x;
        As[(ak + 1) * AS_LD + ar] = av.y;
        As[(ak + 2) * AS_LD + ar] = av.z;
        As[(ak + 3) * AS_LD + ar] = av.w;
        *(float4*)&Bs[br][bc]     = *(const float4*)(B + (size_t)(k0 + br) * BN + bc);
        *(float4*)&Bs[br + 8][bc] = *(const float4*)(B + (size_t)(k0 + br + 8) * BN + bc);
        __syncthreads();
#pragma unroll
        for (int k = 0; k < BK; ++k) {
            float a[8], b[4];
            *(float4*)&a[0] = *(const float4*)&As[k * AS_LD + ty * 8];
            *(float4*)&a[4] = *(const float4*)&As[k * AS_LD + ty * 8 + 4];
            *(float4*)&b[0] = *(const float4*)&Bs[k][tx * 4];
#pragma unroll
            for (int i = 0; i < 8; ++i)
#pragma unroll
                for (int j = 0; j < 4; ++j)
                    acc[i][j] = fmaf(a[i], b[j], acc[i][j]);
        }
        __syncthreads();
    }
#pragma unroll
    for (int i = 0; i < 8; ++i) {
        int r = row0 + ty * 8 + i;
        if (r < M) *(float4*)(C + (size_t)r * BN + tx * 4) = *(float4*)acc[i];
    }
}

// ---------- per-node attention coefficients ----------
__global__ void node_alpha(const float* __restrict__ hp, const float* __restrict__ att,
                           float* __restrict__ asrc, float* __restrict__ adst) {
    int t = blockIdx.x * blockDim.x + threadIdx.x;  // n*HEADS + h
    if (t >= N_NODES * HEADS) return;
    int n = t >> 2, h = t & 3;
    const float* v = hp + (size_t)n * HC + h * HID;
    const float* as = att + h * 2 * HID;
    const float* ad = as + HID;
    float s = 0.f, d = 0.f;
#pragma unroll
    for (int c = 0; c < HID; ++c) { float x = v[c]; s = fmaf(x, as[c], s); d = fmaf(x, ad[c], d); }
    asrc[t] = s;
    adst[t] = d;
}

// ---------- CSR build ----------
__global__ void edge_hist(const int* __restrict__ ei, int* __restrict__ cnt) {
    int e = blockIdx.x * blockDim.x + threadIdx.x;
    if (e >= EE) return;
    int d = (e < N_EDGES) ? ei[N_EDGES + e] : (e - N_EDGES);
    atomicAdd(&cnt[d], 1);
}

// single-block scan over 50000 counts -> rowptr (exclusive) + cursor copy
__global__ void prefix50k(const int* __restrict__ cnt, int* __restrict__ rowptr,
                          int* __restrict__ cursor) {
    __shared__ int wsum[17];
    __shared__ int carry_s;
    int t = threadIdx.x, lane = t & 63, w = t >> 6;
    if (t == 0) carry_s = 0;
    __syncthreads();
    for (int base = 0; base < N_NODES; base += 1024) {
        int i = base + t;
        int v = (i < N_NODES) ? cnt[i] : 0;
        int x = v;
#pragma unroll
        for (int off = 1; off < 64; off <<= 1) {
            int y = __shfl_up(x, off);
            if (lane >= off) x += y;
        }
        if (lane == 63) wsum[w] = x;
        __syncthreads();
        if (t == 0) {
            int run = 0;
#pragma unroll
            for (int k = 0; k < 16; ++k) { int tmp = wsum[k]; wsum[k] = run; run += tmp; }
            wsum[16] = run;
        }
        __syncthreads();
        int excl = carry_s + wsum[w] + x - v;
        if (i < N_NODES) { rowptr[i] = excl; cursor[i] = excl; }
        __syncthreads();
        if (t == 0) carry_s += wsum[16];
        __syncthreads();
    }
    if (t == 0) rowptr[N_NODES] = carry_s;
}

__global__ void edge_scatter(const int* __restrict__ ei, int* __restrict__ cursor,
                             int* __restrict__ ssrc) {
    int e = blockIdx.x * blockDim.x + threadIdx.x;
    if (e >= EE) return;
    int s, d;
    if (e < N_EDGES) { s = ei[e]; d = ei[N_EDGES + e]; } else { s = d = e - N_EDGES; }
    int pos = atomicAdd(&cursor[d], 1);
    ssrc[pos] = s;
}

// ---------- fused per-node GAT aggregate ----------
__device__ __forceinline__ float lrelu(float v) { return v > 0.f ? v : SLOPE * v; }
__device__ __forceinline__ void onl(float l, float& m, float& s) {
    if (l > m) { s = s * expf(m - l) + 1.f; m = l; }
    else       { s += expf(l - m); }
}

#define WPB 4   // waves (nodes) per block
__global__ __launch_bounds__(256) void gat_gather(
    const int* __restrict__ rowptr, const int* __restrict__ ssrc,
    const float* __restrict__ asrc, const float* __restrict__ adst,
    const float* __restrict__ hp, const float* __restrict__ bias,
    float* __restrict__ hout)
{
    __shared__ float s_exp[WPB][64][4];
    __shared__ int   s_src[WPB][64];
    int w = threadIdx.x >> 6;
    int lane = threadIdx.x & 63;
    int node = blockIdx.x * WPB + w;
    if (node >= N_NODES) return;
    int beg = rowptr[node];
    int deg = rowptr[node + 1] - beg;
    float4 ad = *(const float4*)(adst + (size_t)node * 4);

    // ---- phase A: per-lane online softmax stats ----
    float4 m = make_float4(-1e30f, -1e30f, -1e30f, -1e30f);
    float4 z = make_float4(0.f, 0.f, 0.f, 0.f);
    for (int i = lane; i < deg; i += 64) {
        int s = ssrc[beg + i];
        float4 a = *(const float4*)(asrc + (size_t)s * 4);
        onl(lrelu(a.x + ad.x), m.x, z.x);
        onl(lrelu(a.y + ad.y), m.y, z.y);
        onl(lrelu(a.z + ad.z), m.z, z.z);
        onl(lrelu(a.w + ad.w), m.w, z.w);
    }
#pragma unroll
    for (int off = 1; off < 64; off <<= 1) {
        float4 mo, zo;
        mo.x = __shfl_xor(m.x, off); zo.x = __shfl_xor(z.x, off);
        mo.y = __shfl_xor(m.y, off); zo.y = __shfl_xor(z.y, off);
        mo.z = __shfl_xor(m.z, off); zo.z = __shfl_xor(z.z, off);
        mo.w = __shfl_xor(m.w, off); zo.w = __shfl_xor(z.w, off);
        float nm;
        nm = fmaxf(m.x, mo.x); z.x = z.x * expf(m.x - nm) + zo.x * expf(mo.x - nm); m.x = nm;
        nm = fmaxf(m.y, mo.y); z.y = z.y * expf(m.y - nm) + zo.y * expf(mo.y - nm); m.y = nm;
        nm = fmaxf(m.z, mo.z); z.z = z.z * expf(m.z - nm) + zo.z * expf(mo.z - nm); m.z = nm;
        nm = fmaxf(m.w, mo.w); z.w = z.w * expf(m.w - nm) + zo.w * expf(mo.w - nm); m.w = nm;
    }
    int head = lane >> 4;   // lane owns channels {2*lane, 2*lane+1}
    float zh = (head == 0) ? z.x : (head == 1) ? z.y : (head == 2) ? z.z : z.w;
    float zinv = 1.f / zh;

    // ---- phase C: channel-parallel weighted gather ----
    float acc0 = 0.f, acc1 = 0.f;
    for (int c0 = 0; c0 < deg; c0 += 64) {
        int n_ch = min(64, deg - c0);
        if (lane < n_ch) {
            int s = ssrc[beg + c0 + lane];
            float4 a = *(const float4*)(asrc + (size_t)s * 4);
            float4 ex;
            ex.x = expf(lrelu(a.x + ad.x) - m.x);
            ex.y = expf(lrelu(a.y + ad.y) - m.y);
            ex.z = expf(lrelu(a.z + ad.z) - m.z);
            ex.w = expf(lrelu(a.w + ad.w) - m.w);
            *(float4*)&s_exp[w][lane][0] = ex;
            s_src[w][lane] = s;
        }
        asm volatile("s_waitcnt lgkmcnt(0)" ::: "memory");   // same-wave LDS visibility
#pragma unroll 4
        for (int i = 0; i < n_ch; ++i) {
            float e = s_exp[w][i][head];
            int s = s_src[w][i];
            float alpha = e * zinv;
            float2 hv = *(const float2*)(hp + (size_t)s * HC + lane * 2);
            acc0 = fmaf(hv.x, alpha, acc0);
            acc1 = fmaf(hv.y, alpha, acc1);
        }
    }

    float b0 = bias[lane * 2], b1 = bias[lane * 2 + 1];
    float v0 = acc0 + b0; v0 = v0 > 0.f ? v0 : expm1f(v0);
    float v1 = acc1 + b1; v1 = v1 > 0.f ? v1 : expm1f(v1);
    *(float2*)(hout + (size_t)node * HC + lane * 2) = make_float2(v0, v1);
}

// ---------- fused classifier GEMM + log_softmax ----------
__global__ void cls_logsoftmax(const float* __restrict__ h, const float* __restrict__ Wout,
                               float* __restrict__ out) {
    int row = blockIdx.x;
    __shared__ float hs[HC];
    int t = threadIdx.x;  // 64 threads = 1 wave
    hs[t] = h[(size_t)row * HC + t];
    hs[t + 64] = h[(size_t)row * HC + 64 + t];
    __syncthreads();
    float acc = 0.f;
    if (t < CLASSES) {
#pragma unroll
        for (int k = 0; k < HC; ++k) acc = fmaf(hs[k], Wout[k * CLASSES + t], acc);
    }
    float v = (t < CLASSES) ? acc : -1e30f;
#pragma unroll
    for (int off = 32; off; off >>= 1) v = fmaxf(v, __shfl_xor(v, off));
    float m = v;
    float ex = (t < CLASSES) ? expf(acc - m) : 0.f;
#pragma unroll
    for (int off = 32; off; off >>= 1) ex += __shfl_xor(ex, off);
    float ls = logf(ex);
    if (t < CLASSES) out[(size_t)row * CLASSES + t] = acc - m - ls;
}

extern "C" void kernel_launch(void* const* d_in, const int* in_sizes, int n_in,
                              void* d_out, int out_size, void* d_ws, size_t ws_size,
                              hipStream_t stream) {
    const float* x      = (const float*)d_in[0];
    const int*   ei     = (const int*)d_in[1];
    const float* w_in   = (const float*)d_in[2];
    const float* Ws     = (const float*)d_in[3];
    const float* atts   = (const float*)d_in[4];
    const float* biases = (const float*)d_in[5];
    const float* w_out  = (const float*)d_in[6];
    float* out = (float*)d_out;

    // workspace partition
    char* wp = (char*)d_ws;
    float* h    = (float*)wp; wp += (size_t)N_NODES * HC * 4;
    float* h2   = (float*)wp; wp += (size_t)N_NODES * HC * 4;
    float* hp   = (float*)wp; wp += (size_t)N_NODES * HC * 4;
    float* asrc = (float*)wp; wp += (size_t)N_NODES * HEADS * 4;
    float* adst = (float*)wp; wp += (size_t)N_NODES * HEADS * 4;
    int* cnt    = (int*)wp;   wp += (size_t)N_NODES * 4;
    int* rowptr = (int*)wp;   wp += (size_t)(N_NODES + 4) * 4;
    int* cursor = (int*)wp;   wp += (size_t)N_NODES * 4;
    int* ssrc   = (int*)wp;   wp += (size_t)EE * 4;

    // ---- CSR build (once per call; shared by both layers) ----
    hipMemsetAsync(cnt, 0, (size_t)N_NODES * 4, stream);
    edge_hist<<<(EE + 255) / 256, 256, 0, stream>>>(ei, cnt);
    prefix50k<<<1, 1024, 0, stream>>>(cnt, rowptr, cursor);
    edge_scatter<<<(EE + 255) / 256, 256, 0, stream>>>(ei, cursor, ssrc);

    // h = x @ w_in
    gemm_rb<<<(N_NODES + BM - 1) / BM, 256, 0, stream>>>(x, w_in, h, N_NODES, F_IN);

    float* hin = h;
    float* hout = h2;
    for (int l = 0; l < LAYERS; ++l) {
        gemm_rb<<<(N_NODES + BM - 1) / BM, 256, 0, stream>>>(
            hin, Ws + (size_t)l * HC * HC, hp, N_NODES, HC);
        node_alpha<<<(N_NODES * HEADS + 255) / 256, 256, 0, stream>>>(
            hp, atts + (size_t)l * HEADS * 2 * HID, asrc, adst);
        gat_gather<<<(N_NODES + WPB - 1) / WPB, 64 * WPB, 0, stream>>>(
            rowptr, ssrc, asrc, adst, hp, biases + (size_t)l * HC, hout);
        float* tmp = hin; hin = hout; hout = tmp;
    }

    cls_logsoftmax<<<N_NODES, 64, 0, stream>>>(hin, w_out, out);
}

// Round 4
// 436.113 us; speedup vs baseline: 9.0268x; 1.1108x over previous
//
#include <hip/hip_runtime.h>
#include <hip/hip_bf16.h>
#include <math.h>

#define N_NODES 50000
#define N_EDGES 800000
#define F_IN 256
#define HID 32
#define HEADS 4
#define HC 128            // HID*HEADS
#define CLASSES 40
#define LAYERS 2
#define SLOPE 0.1f
#define EE (N_EDGES + N_NODES)   // edges + self loops

typedef unsigned short ushortT;
typedef unsigned int uintT;

__device__ __forceinline__ ushortT f2bu(float f) {
    __hip_bfloat16 h = __float2bfloat16(f);
    ushortT u; __builtin_memcpy(&u, &h, 2); return u;
}

// ---------- register-blocked fp32 GEMM, N fixed at 128, optional bf16 mirror ----------
#define BM 64
#define BN 128
#define BK 16
#define AS_LD 68   // stride 68 floats: 16B-aligned rows, 2-way-bank only (free)
__global__ __launch_bounds__(256) void gemm_rb(const float* __restrict__ A,
                                               const float* __restrict__ B,
                                               float* __restrict__ C,
                                               ushortT* __restrict__ Cb,   // bf16 mirror (may be null)
                                               int M, int K) {
    __shared__ float As[BK * AS_LD];
    __shared__ float Bs[BK][BN];
    int t = threadIdx.x;
    int tx = t & 31;          // col group: cols tx*4 .. tx*4+3
    int ty = t >> 5;          // row group: rows ty*8 .. ty*8+7
    int row0 = blockIdx.x * BM;
    float acc[8][4] = {};
    int ar = t >> 2;
    int ak = (t & 3) * 4;
    int br = t >> 5;
    int bc = (t & 31) * 4;
    for (int k0 = 0; k0 < K; k0 += BK) {
        float4 av = (row0 + ar < M) ? *(const float4*)(A + (size_t)(row0 + ar) * K + k0 + ak)
                                    : make_float4(0.f, 0.f, 0.f, 0.f);
        As[(ak + 0) * AS_LD + ar] = av.x;
        As[(ak + 1) * AS_LD + ar] = av.y;
        As[(ak + 2) * AS_LD + ar] = av.z;
        As[(ak + 3) * AS_LD + ar] = av.w;
        *(float4*)&Bs[br][bc]     = *(const float4*)(B + (size_t)(k0 + br) * BN + bc);
        *(float4*)&Bs[br + 8][bc] = *(const float4*)(B + (size_t)(k0 + br + 8) * BN + bc);
        __syncthreads();
#pragma unroll
        for (int k = 0; k < BK; ++k) {
            float a[8], b[4];
            *(float4*)&a[0] = *(const float4*)&As[k * AS_LD + ty * 8];
            *(float4*)&a[4] = *(const float4*)&As[k * AS_LD + ty * 8 + 4];
            *(float4*)&b[0] = *(const float4*)&Bs[k][tx * 4];
#pragma unroll
            for (int i = 0; i < 8; ++i)
#pragma unroll
                for (int j = 0; j < 4; ++j)
                    acc[i][j] = fmaf(a[i], b[j], acc[i][j]);
        }
        __syncthreads();
    }
#pragma unroll
    for (int i = 0; i < 8; ++i) {
        int r = row0 + ty * 8 + i;
        if (r < M) {
            *(float4*)(C + (size_t)r * BN + tx * 4) = *(float4*)acc[i];
            if (Cb) {
                uint2 p;
                p.x = (uintT)f2bu(acc[i][0]) | ((uintT)f2bu(acc[i][1]) << 16);
                p.y = (uintT)f2bu(acc[i][2]) | ((uintT)f2bu(acc[i][3]) << 16);
                *(uint2*)(Cb + (size_t)r * BN + tx * 4) = p;
            }
        }
    }
}

// ---------- per-node attention coefficients ----------
__global__ void node_alpha(const float* __restrict__ hp, const float* __restrict__ att,
                           float* __restrict__ asrc, float* __restrict__ adst) {
    int t = blockIdx.x * blockDim.x + threadIdx.x;  // n*HEADS + h
    if (t >= N_NODES * HEADS) return;
    int n = t >> 2, h = t & 3;
    const float* v = hp + (size_t)n * HC + h * HID;
    const float* as = att + h * 2 * HID;
    const float* ad = as + HID;
    float s = 0.f, d = 0.f;
#pragma unroll
    for (int c = 0; c < HID; ++c) { float x = v[c]; s = fmaf(x, as[c], s); d = fmaf(x, ad[c], d); }
    asrc[t] = s;
    adst[t] = d;
}

// ---------- CSR build ----------
__global__ void edge_hist(const int* __restrict__ ei, int* __restrict__ cnt) {
    int e = blockIdx.x * blockDim.x + threadIdx.x;
    if (e >= EE) return;
    int d = (e < N_EDGES) ? ei[N_EDGES + e] : (e - N_EDGES);
    atomicAdd(&cnt[d], 1);
}

__global__ void prefix50k(const int* __restrict__ cnt, int* __restrict__ rowptr,
                          int* __restrict__ cursor) {
    __shared__ int wsum[17];
    __shared__ int carry_s;
    int t = threadIdx.x, lane = t & 63, w = t >> 6;
    if (t == 0) carry_s = 0;
    __syncthreads();
    for (int base = 0; base < N_NODES; base += 1024) {
        int i = base + t;
        int v = (i < N_NODES) ? cnt[i] : 0;
        int x = v;
#pragma unroll
        for (int off = 1; off < 64; off <<= 1) {
            int y = __shfl_up(x, off);
            if (lane >= off) x += y;
        }
        if (lane == 63) wsum[w] = x;
        __syncthreads();
        if (t == 0) {
            int run = 0;
#pragma unroll
            for (int k = 0; k < 16; ++k) { int tmp = wsum[k]; wsum[k] = run; run += tmp; }
            wsum[16] = run;
        }
        __syncthreads();
        int excl = carry_s + wsum[w] + x - v;
        if (i < N_NODES) { rowptr[i] = excl; cursor[i] = excl; }
        __syncthreads();
        if (t == 0) carry_s += wsum[16];
        __syncthreads();
    }
    if (t == 0) rowptr[N_NODES] = carry_s;
}

__global__ void edge_scatter(const int* __restrict__ ei, int* __restrict__ cursor,
                             int* __restrict__ ssrc) {
    int e = blockIdx.x * blockDim.x + threadIdx.x;
    if (e >= EE) return;
    int s, d;
    if (e < N_EDGES) { s = ei[e]; d = ei[N_EDGES + e]; } else { s = d = e - N_EDGES; }
    int pos = atomicAdd(&cursor[d], 1);
    ssrc[pos] = s;
}

// ---------- fused per-node GAT aggregate: exact 2-pass softmax, bf16 hp gather ----------
__device__ __forceinline__ float lrelu(float v) { return v > 0.f ? v : SLOPE * v; }

#define WPB 4   // waves (nodes) per block
__global__ __launch_bounds__(256) void gat_gather(
    const int* __restrict__ rowptr, const int* __restrict__ ssrc,
    const float* __restrict__ asrc, const float* __restrict__ adst,
    const ushortT* __restrict__ hpb, const float* __restrict__ bias,
    float* __restrict__ hout)
{
    __shared__ float s_exp[WPB][64][4];
    __shared__ int   s_src[WPB][64];
    int w = threadIdx.x >> 6;
    int lane = threadIdx.x & 63;
    int node = blockIdx.x * WPB + w;
    if (node >= N_NODES) return;
    int beg = rowptr[node];
    int deg = rowptr[node + 1] - beg;
    float4 ad = *(const float4*)(adst + (size_t)node * 4);

    // ---- phase A: max only (exact 2-pass softmax) ----
    float4 m = make_float4(-1e30f, -1e30f, -1e30f, -1e30f);
    for (int i = lane; i < deg; i += 64) {
        int s = ssrc[beg + i];
        float4 a = *(const float4*)(asrc + (size_t)s * 4);
        m.x = fmaxf(m.x, lrelu(a.x + ad.x));
        m.y = fmaxf(m.y, lrelu(a.y + ad.y));
        m.z = fmaxf(m.z, lrelu(a.z + ad.z));
        m.w = fmaxf(m.w, lrelu(a.w + ad.w));
    }
#pragma unroll
    for (int off = 1; off < 64; off <<= 1) {
        m.x = fmaxf(m.x, __shfl_xor(m.x, off));
        m.y = fmaxf(m.y, __shfl_xor(m.y, off));
        m.z = fmaxf(m.z, __shfl_xor(m.z, off));
        m.w = fmaxf(m.w, __shfl_xor(m.w, off));
    }
    int head = lane >> 4;   // lane owns channels {2*lane, 2*lane+1}

    // ---- phase C: exp once per edge, accumulate unnormalized msg + z ----
    float acc0 = 0.f, acc1 = 0.f;
    float4 zp = make_float4(0.f, 0.f, 0.f, 0.f);
    const ushortT* hrow = hpb + lane * 2;
    for (int c0 = 0; c0 < deg; c0 += 64) {
        int n_ch = min(64, deg - c0);
        if (lane < n_ch) {
            int s = ssrc[beg + c0 + lane];
            float4 a = *(const float4*)(asrc + (size_t)s * 4);
            float4 ex;
            ex.x = expf(lrelu(a.x + ad.x) - m.x);
            ex.y = expf(lrelu(a.y + ad.y) - m.y);
            ex.z = expf(lrelu(a.z + ad.z) - m.z);
            ex.w = expf(lrelu(a.w + ad.w) - m.w);
            *(float4*)&s_exp[w][lane][0] = ex;
            s_src[w][lane] = s;
            zp.x += ex.x; zp.y += ex.y; zp.z += ex.z; zp.w += ex.w;
        }
        asm volatile("s_waitcnt lgkmcnt(0)" ::: "memory");   // same-wave LDS visibility
#pragma unroll 4
        for (int i = 0; i < n_ch; ++i) {
            float e = s_exp[w][i][head];
            int s = s_src[w][i];
            uintT u = *(const uintT*)(hrow + (size_t)s * HC);
            float h0 = __uint_as_float(u << 16);
            float h1 = __uint_as_float(u & 0xffff0000u);
            acc0 = fmaf(h0, e, acc0);
            acc1 = fmaf(h1, e, acc1);
        }
    }
    // ---- z reduction + normalize + bias + ELU + store ----
#pragma unroll
    for (int off = 1; off < 64; off <<= 1) {
        zp.x += __shfl_xor(zp.x, off);
        zp.y += __shfl_xor(zp.y, off);
        zp.z += __shfl_xor(zp.z, off);
        zp.w += __shfl_xor(zp.w, off);
    }
    float zh = (head == 0) ? zp.x : (head == 1) ? zp.y : (head == 2) ? zp.z : zp.w;
    float zinv = 1.f / zh;
    float b0 = bias[lane * 2], b1 = bias[lane * 2 + 1];
    float v0 = acc0 * zinv + b0; v0 = v0 > 0.f ? v0 : expm1f(v0);
    float v1 = acc1 * zinv + b1; v1 = v1 > 0.f ? v1 : expm1f(v1);
    *(float2*)(hout + (size_t)node * HC + lane * 2) = make_float2(v0, v1);
}

// ---------- fused classifier GEMM + log_softmax ----------
__global__ void cls_logsoftmax(const float* __restrict__ h, const float* __restrict__ Wout,
                               float* __restrict__ out) {
    int row = blockIdx.x;
    __shared__ float hs[HC];
    int t = threadIdx.x;  // 64 threads = 1 wave
    hs[t] = h[(size_t)row * HC + t];
    hs[t + 64] = h[(size_t)row * HC + 64 + t];
    __syncthreads();
    float acc = 0.f;
    if (t < CLASSES) {
#pragma unroll
        for (int k = 0; k < HC; ++k) acc = fmaf(hs[k], Wout[k * CLASSES + t], acc);
    }
    float v = (t < CLASSES) ? acc : -1e30f;
#pragma unroll
    for (int off = 32; off; off >>= 1) v = fmaxf(v, __shfl_xor(v, off));
    float m = v;
    float ex = (t < CLASSES) ? expf(acc - m) : 0.f;
#pragma unroll
    for (int off = 32; off; off >>= 1) ex += __shfl_xor(ex, off);
    float ls = logf(ex);
    if (t < CLASSES) out[(size_t)row * CLASSES + t] = acc - m - ls;
}

extern "C" void kernel_launch(void* const* d_in, const int* in_sizes, int n_in,
                              void* d_out, int out_size, void* d_ws, size_t ws_size,
                              hipStream_t stream) {
    const float* x      = (const float*)d_in[0];
    const int*   ei     = (const int*)d_in[1];
    const float* w_in   = (const float*)d_in[2];
    const float* Ws     = (const float*)d_in[3];
    const float* atts   = (const float*)d_in[4];
    const float* biases = (const float*)d_in[5];
    const float* w_out  = (const float*)d_in[6];
    float* out = (float*)d_out;

    // workspace partition
    char* wp = (char*)d_ws;
    float* h    = (float*)wp; wp += (size_t)N_NODES * HC * 4;
    float* h2   = (float*)wp; wp += (size_t)N_NODES * HC * 4;
    float* hp   = (float*)wp; wp += (size_t)N_NODES * HC * 4;
    ushortT* hpb = (ushortT*)wp; wp += (size_t)N_NODES * HC * 2;
    float* asrc = (float*)wp; wp += (size_t)N_NODES * HEADS * 4;
    float* adst = (float*)wp; wp += (size_t)N_NODES * HEADS * 4;
    int* cnt    = (int*)wp;   wp += (size_t)N_NODES * 4;
    int* rowptr = (int*)wp;   wp += (size_t)(N_NODES + 4) * 4;
    int* cursor = (int*)wp;   wp += (size_t)N_NODES * 4;
    int* ssrc   = (int*)wp;   wp += (size_t)EE * 4;

    // ---- CSR build (once per call; shared by both layers) ----
    hipMemsetAsync(cnt, 0, (size_t)N_NODES * 4, stream);
    edge_hist<<<(EE + 255) / 256, 256, 0, stream>>>(ei, cnt);
    prefix50k<<<1, 1024, 0, stream>>>(cnt, rowptr, cursor);
    edge_scatter<<<(EE + 255) / 256, 256, 0, stream>>>(ei, cursor, ssrc);

    // h = x @ w_in  (no bf16 mirror needed)
    gemm_rb<<<(N_NODES + BM - 1) / BM, 256, 0, stream>>>(x, w_in, h, (ushortT*)nullptr,
                                                         N_NODES, F_IN);

    float* hin = h;
    float* hout = h2;
    for (int l = 0; l < LAYERS; ++l) {
        gemm_rb<<<(N_NODES + BM - 1) / BM, 256, 0, stream>>>(
            hin, Ws + (size_t)l * HC * HC, hp, hpb, N_NODES, HC);
        node_alpha<<<(N_NODES * HEADS + 255) / 256, 256, 0, stream>>>(
            hp, atts + (size_t)l * HEADS * 2 * HID, asrc, adst);
        gat_gather<<<(N_NODES + WPB - 1) / WPB, 64 * WPB, 0, stream>>>(
            rowptr, ssrc, asrc, adst, hpb, biases + (size_t)l * HC, hout);
        float* tmp = hin; hin = hout; hout = tmp;
    }

    cls_logsoftmax<<<N_NODES, 64, 0, stream>>>(hin, w_out, out);
}

// Round 5
// 364.807 us; speedup vs baseline: 10.7912x; 1.1955x over previous
//
#include <hip/hip_runtime.h>
#include <hip/hip_bf16.h>
#include <math.h>

#define N_NODES 50000
#define N_EDGES 800000
#define F_IN 256
#define HID 32
#define HEADS 4
#define HC 128            // HID*HEADS
#define CLASSES 40
#define LAYERS 2
#define SLOPE 0.1f
#define EE (N_EDGES + N_NODES)   // edges + self loops

typedef unsigned short ushortT;
typedef unsigned int uintT;
typedef __attribute__((ext_vector_type(8))) short short8v;   // 8 bf16 = 4 VGPRs
typedef __attribute__((ext_vector_type(4))) float f32x4;

__device__ __forceinline__ ushortT f2bu(float f) {
    __hip_bfloat16 h = __float2bfloat16(f);
    ushortT u; __builtin_memcpy(&u, &h, 2); return u;
}

// ---------- weight transpose+convert: W[K][128] fp32 -> WT[128][K] bf16 ----------
__global__ void wconv(const float* __restrict__ W, ushortT* __restrict__ WT, int K) {
    int i = blockIdx.x * 256 + threadIdx.x;
    if (i >= K * 128) return;
    int r = i >> 7, c = i & 127;
    WT[(size_t)c * K + r] = f2bu(W[i]);
}

// ---------- MFMA bf16 GEMM, N fixed 128: C[M,128] = A[M,K] @ B[K,128] ----------
// B passed pre-transposed bf16: BT[128][K]. A: fp32 (converted in staging) or bf16.
// Block: 256 thr = 4 waves; wave w owns rows w*16..+15; 8 col-tiles of 16.
// LDS tiles padded to stride 40 bf16 (80 B): 2-way bank aliasing only (free).
#define AS_LD 40
template<bool AF32>
__global__ __launch_bounds__(256) void gemm_mfma(const void* __restrict__ Aptr,
                                                 const ushortT* __restrict__ BT,
                                                 float* __restrict__ Cf,      // may be null
                                                 ushortT* __restrict__ Cb,    // may be null
                                                 int M, int K) {
    __shared__ ushortT As[64 * AS_LD];    // [row][k<32]
    __shared__ ushortT Bs[128 * AS_LD];   // [col][k<32]
    int t = threadIdx.x;
    int w = t >> 6, lane = t & 63;
    int row0 = blockIdx.x * 64;
    // A staging: thread t covers (row ar, k ak..ak+7)
    int ar = t >> 2, ak = (t & 3) * 8;
    // B staging: thread t covers (col bcol, k bks..bks+15)
    int bcol = t >> 1, bks = (t & 1) * 16;
    int wr = w * 16;
    int arow = wr + (lane & 15);
    int ak8 = (lane >> 4) * 8;
    f32x4 acc[8] = {};

    for (int k0 = 0; k0 < K; k0 += 32) {
        int grow = row0 + ar;
        if (AF32) {
            const float* A = (const float*)Aptr;
            float4 v0 = make_float4(0.f, 0.f, 0.f, 0.f), v1 = v0;
            if (grow < M) {
                const float* ap = A + (size_t)grow * K + k0 + ak;
                v0 = *(const float4*)ap;
                v1 = *(const float4*)(ap + 4);
            }
            uint4 p;
            p.x = (uintT)f2bu(v0.x) | ((uintT)f2bu(v0.y) << 16);
            p.y = (uintT)f2bu(v0.z) | ((uintT)f2bu(v0.w) << 16);
            p.z = (uintT)f2bu(v1.x) | ((uintT)f2bu(v1.y) << 16);
            p.w = (uintT)f2bu(v1.z) | ((uintT)f2bu(v1.w) << 16);
            *(uint4*)&As[ar * AS_LD + ak] = p;
        } else {
            const ushortT* A = (const ushortT*)Aptr;
            uint4 p = make_uint4(0, 0, 0, 0);
            if (grow < M) p = *(const uint4*)(A + (size_t)grow * K + k0 + ak);
            *(uint4*)&As[ar * AS_LD + ak] = p;
        }
        {
            const ushortT* bp = BT + (size_t)bcol * K + k0 + bks;
            *(uint4*)&Bs[bcol * AS_LD + bks]     = *(const uint4*)bp;
            *(uint4*)&Bs[bcol * AS_LD + bks + 8] = *(const uint4*)(bp + 8);
        }
        __syncthreads();
        short8v a = *(short8v*)&As[arow * AS_LD + ak8];
#pragma unroll
        for (int c = 0; c < 8; ++c) {
            short8v b = *(short8v*)&Bs[(c * 16 + (lane & 15)) * AS_LD + ak8];
            acc[c] = __builtin_amdgcn_mfma_f32_16x16x32_bf16(a, b, acc[c], 0, 0, 0);
        }
        __syncthreads();
    }
    // epilogue: C/D layout col = lane&15, row = (lane>>4)*4 + r  [m89/m91 verified]
    int r0 = row0 + wr + ((lane >> 4) << 2);
    int col = lane & 15;
#pragma unroll
    for (int c = 0; c < 8; ++c) {
        int cc = c * 16 + col;
#pragma unroll
        for (int r = 0; r < 4; ++r) {
            int rr = r0 + r;
            if (rr < M) {
                if (Cf) Cf[(size_t)rr * 128 + cc] = acc[c][r];
                if (Cb) Cb[(size_t)rr * 128 + cc] = f2bu(acc[c][r]);
            }
        }
    }
}

// ---------- per-node attention coefficients ----------
__global__ void node_alpha(const float* __restrict__ hp, const float* __restrict__ att,
                           float* __restrict__ asrc, float* __restrict__ adst) {
    int t = blockIdx.x * blockDim.x + threadIdx.x;  // n*HEADS + h
    if (t >= N_NODES * HEADS) return;
    int n = t >> 2, h = t & 3;
    const float* v = hp + (size_t)n * HC + h * HID;
    const float* as = att + h * 2 * HID;
    const float* ad = as + HID;
    float s = 0.f, d = 0.f;
#pragma unroll
    for (int c = 0; c < HID; ++c) { float x = v[c]; s = fmaf(x, as[c], s); d = fmaf(x, ad[c], d); }
    asrc[t] = s;
    adst[t] = d;
}

// ---------- CSR build ----------
__global__ void edge_hist(const int* __restrict__ ei, int* __restrict__ cnt) {
    int e = blockIdx.x * blockDim.x + threadIdx.x;
    if (e >= EE) return;
    int d = (e < N_EDGES) ? ei[N_EDGES + e] : (e - N_EDGES);
    atomicAdd(&cnt[d], 1);
}

__global__ void prefix50k(const int* __restrict__ cnt, int* __restrict__ rowptr,
                          int* __restrict__ cursor) {
    __shared__ int wsum[17];
    __shared__ int carry_s;
    int t = threadIdx.x, lane = t & 63, w = t >> 6;
    if (t == 0) carry_s = 0;
    __syncthreads();
    for (int base = 0; base < N_NODES; base += 1024) {
        int i = base + t;
        int v = (i < N_NODES) ? cnt[i] : 0;
        int x = v;
#pragma unroll
        for (int off = 1; off < 64; off <<= 1) {
            int y = __shfl_up(x, off);
            if (lane >= off) x += y;
        }
        if (lane == 63) wsum[w] = x;
        __syncthreads();
        if (t == 0) {
            int run = 0;
#pragma unroll
            for (int k = 0; k < 16; ++k) { int tmp = wsum[k]; wsum[k] = run; run += tmp; }
            wsum[16] = run;
        }
        __syncthreads();
        int excl = carry_s + wsum[w] + x - v;
        if (i < N_NODES) { rowptr[i] = excl; cursor[i] = excl; }
        __syncthreads();
        if (t == 0) carry_s += wsum[16];
        __syncthreads();
    }
    if (t == 0) rowptr[N_NODES] = carry_s;
}

__global__ void edge_scatter(const int* __restrict__ ei, int* __restrict__ cursor,
                             int* __restrict__ ssrc) {
    int e = blockIdx.x * blockDim.x + threadIdx.x;
    if (e >= EE) return;
    int s, d;
    if (e < N_EDGES) { s = ei[e]; d = ei[N_EDGES + e]; } else { s = d = e - N_EDGES; }
    int pos = atomicAdd(&cursor[d], 1);
    ssrc[pos] = s;
}

// ---------- fused per-node GAT aggregate: exact 2-pass softmax, bf16 hp gather ----------
__device__ __forceinline__ float lrelu(float v) { return v > 0.f ? v : SLOPE * v; }

#define WPB 4   // waves (nodes) per block
__global__ __launch_bounds__(256) void gat_gather(
    const int* __restrict__ rowptr, const int* __restrict__ ssrc,
    const float* __restrict__ asrc, const float* __restrict__ adst,
    const ushortT* __restrict__ hpb, const float* __restrict__ bias,
    float* __restrict__ foutF, ushortT* __restrict__ foutB)
{
    __shared__ float s_exp[WPB][64][4];
    __shared__ int   s_src[WPB][64];
    int w = threadIdx.x >> 6;
    int lane = threadIdx.x & 63;
    int node = blockIdx.x * WPB + w;
    if (node >= N_NODES) return;
    int beg = rowptr[node];
    int deg = rowptr[node + 1] - beg;
    float4 ad = *(const float4*)(adst + (size_t)node * 4);

    // ---- phase A: max only ----
    float4 m = make_float4(-1e30f, -1e30f, -1e30f, -1e30f);
    for (int i = lane; i < deg; i += 64) {
        int s = ssrc[beg + i];
        float4 a = *(const float4*)(asrc + (size_t)s * 4);
        m.x = fmaxf(m.x, lrelu(a.x + ad.x));
        m.y = fmaxf(m.y, lrelu(a.y + ad.y));
        m.z = fmaxf(m.z, lrelu(a.z + ad.z));
        m.w = fmaxf(m.w, lrelu(a.w + ad.w));
    }
#pragma unroll
    for (int off = 1; off < 64; off <<= 1) {
        m.x = fmaxf(m.x, __shfl_xor(m.x, off));
        m.y = fmaxf(m.y, __shfl_xor(m.y, off));
        m.z = fmaxf(m.z, __shfl_xor(m.z, off));
        m.w = fmaxf(m.w, __shfl_xor(m.w, off));
    }
    int head = lane >> 4;   // lane owns channels {2*lane, 2*lane+1}

    // ---- phase C: exp once per edge, unnormalized msg + z ----
    float acc0 = 0.f, acc1 = 0.f;
    float4 zp = make_float4(0.f, 0.f, 0.f, 0.f);
    const ushortT* hrow = hpb + lane * 2;
    for (int c0 = 0; c0 < deg; c0 += 64) {
        int n_ch = min(64, deg - c0);
        if (lane < n_ch) {
            int s = ssrc[beg + c0 + lane];
            float4 a = *(const float4*)(asrc + (size_t)s * 4);
            float4 ex;
            ex.x = expf(lrelu(a.x + ad.x) - m.x);
            ex.y = expf(lrelu(a.y + ad.y) - m.y);
            ex.z = expf(lrelu(a.z + ad.z) - m.z);
            ex.w = expf(lrelu(a.w + ad.w) - m.w);
            *(float4*)&s_exp[w][lane][0] = ex;
            s_src[w][lane] = s;
            zp.x += ex.x; zp.y += ex.y; zp.z += ex.z; zp.w += ex.w;
        }
        asm volatile("s_waitcnt lgkmcnt(0)" ::: "memory");
#pragma unroll 4
        for (int i = 0; i < n_ch; ++i) {
            float e = s_exp[w][i][head];
            int s = s_src[w][i];
            uintT u = *(const uintT*)(hrow + (size_t)s * HC);
            float h0 = __uint_as_float(u << 16);
            float h1 = __uint_as_float(u & 0xffff0000u);
            acc0 = fmaf(h0, e, acc0);
            acc1 = fmaf(h1, e, acc1);
        }
    }
#pragma unroll
    for (int off = 1; off < 64; off <<= 1) {
        zp.x += __shfl_xor(zp.x, off);
        zp.y += __shfl_xor(zp.y, off);
        zp.z += __shfl_xor(zp.z, off);
        zp.w += __shfl_xor(zp.w, off);
    }
    float zh = (head == 0) ? zp.x : (head == 1) ? zp.y : (head == 2) ? zp.z : zp.w;
    float zinv = 1.f / zh;
    float b0 = bias[lane * 2], b1 = bias[lane * 2 + 1];
    float v0 = acc0 * zinv + b0; v0 = v0 > 0.f ? v0 : expm1f(v0);
    float v1 = acc1 * zinv + b1; v1 = v1 > 0.f ? v1 : expm1f(v1);
    if (foutF) *(float2*)(foutF + (size_t)node * HC + lane * 2) = make_float2(v0, v1);
    if (foutB) *(uintT*)(foutB + (size_t)node * HC + lane * 2) =
        (uintT)f2bu(v0) | ((uintT)f2bu(v1) << 16);
}

// ---------- fused classifier GEMM + log_softmax ----------
__global__ void cls_logsoftmax(const float* __restrict__ h, const float* __restrict__ Wout,
                               float* __restrict__ out) {
    int row = blockIdx.x;
    __shared__ float hs[HC];
    int t = threadIdx.x;  // 64 threads = 1 wave
    hs[t] = h[(size_t)row * HC + t];
    hs[t + 64] = h[(size_t)row * HC + 64 + t];
    __syncthreads();
    float acc = 0.f;
    if (t < CLASSES) {
#pragma unroll
        for (int k = 0; k < HC; ++k) acc = fmaf(hs[k], Wout[k * CLASSES + t], acc);
    }
    float v = (t < CLASSES) ? acc : -1e30f;
#pragma unroll
    for (int off = 32; off; off >>= 1) v = fmaxf(v, __shfl_xor(v, off));
    float m = v;
    float ex = (t < CLASSES) ? expf(acc - m) : 0.f;
#pragma unroll
    for (int off = 32; off; off >>= 1) ex += __shfl_xor(ex, off);
    float ls = logf(ex);
    if (t < CLASSES) out[(size_t)row * CLASSES + t] = acc - m - ls;
}

extern "C" void kernel_launch(void* const* d_in, const int* in_sizes, int n_in,
                              void* d_out, int out_size, void* d_ws, size_t ws_size,
                              hipStream_t stream) {
    const float* x      = (const float*)d_in[0];
    const int*   ei     = (const int*)d_in[1];
    const float* w_in   = (const float*)d_in[2];
    const float* Ws     = (const float*)d_in[3];
    const float* atts   = (const float*)d_in[4];
    const float* biases = (const float*)d_in[5];
    const float* w_out  = (const float*)d_in[6];
    float* out = (float*)d_out;

    // workspace partition
    char* wp = (char*)d_ws;
    ushortT* hb0 = (ushortT*)wp; wp += (size_t)N_NODES * HC * 2;   // bf16 h (G0 out)
    ushortT* hb1 = (ushortT*)wp; wp += (size_t)N_NODES * HC * 2;   // bf16 gat_l0 out
    float* hpf   = (float*)wp;   wp += (size_t)N_NODES * HC * 4;   // fp32 hp
    ushortT* hpb = (ushortT*)wp; wp += (size_t)N_NODES * HC * 2;   // bf16 hp
    float* hf    = (float*)wp;   wp += (size_t)N_NODES * HC * 4;   // fp32 gat_l1 out
    float* asrc  = (float*)wp;   wp += (size_t)N_NODES * HEADS * 4;
    float* adst  = (float*)wp;   wp += (size_t)N_NODES * HEADS * 4;
    int* cnt     = (int*)wp;     wp += (size_t)N_NODES * 4;
    int* rowptr  = (int*)wp;     wp += (size_t)(N_NODES + 4) * 4;
    int* cursor  = (int*)wp;     wp += (size_t)N_NODES * 4;
    int* ssrc    = (int*)wp;     wp += (size_t)EE * 4;
    ushortT* w_inT = (ushortT*)wp; wp += (size_t)HC * F_IN * 2;
    ushortT* WsT   = (ushortT*)wp; wp += (size_t)LAYERS * HC * HC * 2;

    // ---- CSR build ----
    hipMemsetAsync(cnt, 0, (size_t)N_NODES * 4, stream);
    edge_hist<<<(EE + 255) / 256, 256, 0, stream>>>(ei, cnt);
    prefix50k<<<1, 1024, 0, stream>>>(cnt, rowptr, cursor);
    edge_scatter<<<(EE + 255) / 256, 256, 0, stream>>>(ei, cursor, ssrc);

    // ---- weight convert+transpose ----
    wconv<<<(F_IN * HC + 255) / 256, 256, 0, stream>>>(w_in, w_inT, F_IN);
    wconv<<<(HC * HC + 255) / 256, 256, 0, stream>>>(Ws, WsT, HC);
    wconv<<<(HC * HC + 255) / 256, 256, 0, stream>>>(Ws + (size_t)HC * HC, WsT + (size_t)HC * HC, HC);

    int gblk = (N_NODES + 63) / 64;
    // h = x @ w_in  -> bf16 only
    gemm_mfma<true><<<gblk, 256, 0, stream>>>(x, w_inT, (float*)nullptr, hb0, N_NODES, F_IN);

    const ushortT* hin_b = hb0;
    for (int l = 0; l < LAYERS; ++l) {
        gemm_mfma<false><<<gblk, 256, 0, stream>>>(hin_b, WsT + (size_t)l * HC * HC,
                                                   hpf, hpb, N_NODES, HC);
        node_alpha<<<(N_NODES * HEADS + 255) / 256, 256, 0, stream>>>(
            hpf, atts + (size_t)l * HEADS * 2 * HID, asrc, adst);
        gat_gather<<<(N_NODES + WPB - 1) / WPB, 64 * WPB, 0, stream>>>(
            rowptr, ssrc, asrc, adst, hpb, biases + (size_t)l * HC,
            (l == LAYERS - 1) ? hf : (float*)nullptr,
            (l == LAYERS - 1) ? (ushortT*)nullptr : hb1);
        hin_b = hb1;
    }

    cls_logsoftmax<<<N_NODES, 64, 0, stream>>>(hf, w_out, out);
}

// Round 6
// 273.794 us; speedup vs baseline: 14.3783x; 1.3324x over previous
//
#include <hip/hip_runtime.h>
#include <hip/hip_bf16.h>
#include <math.h>

#define N_NODES 50000
#define N_EDGES 800000
#define F_IN 256
#define HID 32
#define HEADS 4
#define HC 128            // HID*HEADS
#define CLASSES 40
#define LAYERS 2
#define SLOPE 0.1f
#define EE (N_EDGES + N_NODES)   // edges + self loops

#define BSHIFT 9
#define NBUCK 98          // ceil(50000 / 512)
#define CHUNK 4096        // edges per block in bucket passes
#define NBLK_E ((EE + CHUNK - 1) / CHUNK)

typedef unsigned short ushortT;
typedef unsigned int uintT;
typedef __attribute__((ext_vector_type(8))) short short8v;   // 8 bf16 = 4 VGPRs
typedef __attribute__((ext_vector_type(4))) float f32x4;

__device__ __forceinline__ ushortT f2bu(float f) {
    __hip_bfloat16 h = __float2bfloat16(f);
    ushortT u; __builtin_memcpy(&u, &h, 2); return u;
}

// ---------- weight transpose+convert: W[K][128] fp32 -> WT[128][K] bf16 ----------
__global__ void wconv(const float* __restrict__ W, ushortT* __restrict__ WT, int K) {
    int i = blockIdx.x * 256 + threadIdx.x;
    if (i >= K * 128) return;
    int r = i >> 7, c = i & 127;
    WT[(size_t)c * K + r] = f2bu(W[i]);
}

// ---------- MFMA bf16 GEMM, N fixed 128 ----------
#define AS_LD 40
template<bool AF32>
__global__ __launch_bounds__(256) void gemm_mfma(const void* __restrict__ Aptr,
                                                 const ushortT* __restrict__ BT,
                                                 float* __restrict__ Cf,      // may be null
                                                 ushortT* __restrict__ Cb,    // may be null
                                                 int M, int K) {
    __shared__ ushortT As[64 * AS_LD];    // [row][k<32]
    __shared__ ushortT Bs[128 * AS_LD];   // [col][k<32]
    int t = threadIdx.x;
    int w = t >> 6, lane = t & 63;
    int row0 = blockIdx.x * 64;
    int ar = t >> 2, ak = (t & 3) * 8;
    int bcol = t >> 1, bks = (t & 1) * 16;
    int wr = w * 16;
    int arow = wr + (lane & 15);
    int ak8 = (lane >> 4) * 8;
    f32x4 acc[8] = {};

    for (int k0 = 0; k0 < K; k0 += 32) {
        int grow = row0 + ar;
        if (AF32) {
            const float* A = (const float*)Aptr;
            float4 v0 = make_float4(0.f, 0.f, 0.f, 0.f), v1 = v0;
            if (grow < M) {
                const float* ap = A + (size_t)grow * K + k0 + ak;
                v0 = *(const float4*)ap;
                v1 = *(const float4*)(ap + 4);
            }
            uint4 p;
            p.x = (uintT)f2bu(v0.x) | ((uintT)f2bu(v0.y) << 16);
            p.y = (uintT)f2bu(v0.z) | ((uintT)f2bu(v0.w) << 16);
            p.z = (uintT)f2bu(v1.x) | ((uintT)f2bu(v1.y) << 16);
            p.w = (uintT)f2bu(v1.z) | ((uintT)f2bu(v1.w) << 16);
            *(uint4*)&As[ar * AS_LD + ak] = p;
        } else {
            const ushortT* A = (const ushortT*)Aptr;
            uint4 p = make_uint4(0, 0, 0, 0);
            if (grow < M) p = *(const uint4*)(A + (size_t)grow * K + k0 + ak);
            *(uint4*)&As[ar * AS_LD + ak] = p;
        }
        {
            const ushortT* bp = BT + (size_t)bcol * K + k0 + bks;
            *(uint4*)&Bs[bcol * AS_LD + bks]     = *(const uint4*)bp;
            *(uint4*)&Bs[bcol * AS_LD + bks + 8] = *(const uint4*)(bp + 8);
        }
        __syncthreads();
        short8v a = *(short8v*)&As[arow * AS_LD + ak8];
#pragma unroll
        for (int c = 0; c < 8; ++c) {
            short8v b = *(short8v*)&Bs[(c * 16 + (lane & 15)) * AS_LD + ak8];
            acc[c] = __builtin_amdgcn_mfma_f32_16x16x32_bf16(a, b, acc[c], 0, 0, 0);
        }
        __syncthreads();
    }
    int r0 = row0 + wr + ((lane >> 4) << 2);
    int col = lane & 15;
#pragma unroll
    for (int c = 0; c < 8; ++c) {
        int cc = c * 16 + col;
#pragma unroll
        for (int r = 0; r < 4; ++r) {
            int rr = r0 + r;
            if (rr < M) {
                if (Cf) Cf[(size_t)rr * 128 + cc] = acc[c][r];
                if (Cb) Cb[(size_t)rr * 128 + cc] = f2bu(acc[c][r]);
            }
        }
    }
}

// ---------- per-node attention coefficients ----------
__global__ void node_alpha(const float* __restrict__ hp, const float* __restrict__ att,
                           float* __restrict__ asrc, float* __restrict__ adst) {
    int t = blockIdx.x * blockDim.x + threadIdx.x;  // n*HEADS + h
    if (t >= N_NODES * HEADS) return;
    int n = t >> 2, h = t & 3;
    const float* v = hp + (size_t)n * HC + h * HID;
    const float* as = att + h * 2 * HID;
    const float* ad = as + HID;
    float s = 0.f, d = 0.f;
#pragma unroll
    for (int c = 0; c < HID; ++c) { float x = v[c]; s = fmaf(x, as[c], s); d = fmaf(x, ad[c], d); }
    asrc[t] = s;
    adst[t] = d;
}

// ---------- CSR build via two-level bucket sort (write-local scatters) ----------
__global__ __launch_bounds__(256) void bucket_count(const int* __restrict__ ei,
                                                    int* __restrict__ bcnt) {
    __shared__ int hist[NBUCK];
    int t = threadIdx.x;
    if (t < NBUCK) hist[t] = 0;
    __syncthreads();
    int base = blockIdx.x * CHUNK;
    int end = min(base + CHUNK, EE);
    for (int i = base + t; i < end; i += 256) {
        int d = (i < N_EDGES) ? ei[N_EDGES + i] : (i - N_EDGES);
        atomicAdd(&hist[d >> BSHIFT], 1);
    }
    __syncthreads();
    if (t < NBUCK && hist[t]) atomicAdd(&bcnt[t], hist[t]);
}

__global__ void bucket_scan(const int* __restrict__ bcnt, int* __restrict__ bbase,
                            int* __restrict__ gcur, int* __restrict__ rowptr) {
    if (threadIdx.x == 0) {
        int run = 0;
        for (int b = 0; b < NBUCK; ++b) { bbase[b] = run; gcur[b] = run; run += bcnt[b]; }
        bbase[NBUCK] = run;
        rowptr[N_NODES] = run;   // == EE
    }
}

__global__ __launch_bounds__(256) void bucket_scatter(const int* __restrict__ ei,
                                                      int* __restrict__ gcur,
                                                      uint2* __restrict__ ebuf) {
    __shared__ int hist[NBUCK];
    __shared__ int rbase[NBUCK];
    int t = threadIdx.x;
    if (t < NBUCK) hist[t] = 0;
    __syncthreads();
    int base = blockIdx.x * CHUNK;
    int end = min(base + CHUNK, EE);
    for (int i = base + t; i < end; i += 256) {
        int d = (i < N_EDGES) ? ei[N_EDGES + i] : (i - N_EDGES);
        atomicAdd(&hist[d >> BSHIFT], 1);
    }
    __syncthreads();
    if (t < NBUCK) {
        int c = hist[t];
        rbase[t] = c ? atomicAdd(&gcur[t], c) : 0;
    }
    __syncthreads();
    if (t < NBUCK) hist[t] = 0;
    __syncthreads();
    for (int i = base + t; i < end; i += 256) {
        int s, d;
        if (i < N_EDGES) { s = ei[i]; d = ei[N_EDGES + i]; } else { s = d = i - N_EDGES; }
        int b = d >> BSHIFT;
        int pos = rbase[b] + atomicAdd(&hist[b], 1);
        ebuf[pos] = make_uint2((uintT)s, (uintT)d);
    }
}

// one block per bucket: per-node counts in LDS, local scan -> rowptr, local scatter -> ssrc
__global__ __launch_bounds__(256) void csr_local(const uint2* __restrict__ ebuf,
                                                 const int* __restrict__ bbase,
                                                 int* __restrict__ rowptr,
                                                 int* __restrict__ ssrc) {
    __shared__ int cnt[512];
    __shared__ int cur[512];
    __shared__ int wsum[4];
    int b = blockIdx.x;
    int t = threadIdx.x;
    int node0 = b << BSHIFT;
    int nb = min(512, N_NODES - node0);
    int beg = bbase[b], end = bbase[b + 1];
    cnt[t] = 0; cnt[t + 256] = 0;
    __syncthreads();
    for (int i = beg + t; i < end; i += 256)
        atomicAdd(&cnt[ebuf[i].y & 511], 1);
    __syncthreads();
    // exclusive scan of cnt[0..511]: thread t owns pair (2t, 2t+1)
    int v0 = cnt[2 * t], v1 = cnt[2 * t + 1];
    int s = v0 + v1;
    int lane = t & 63, w = t >> 6;
    int x = s;
#pragma unroll
    for (int off = 1; off < 64; off <<= 1) { int y = __shfl_up(x, off); if (lane >= off) x += y; }
    if (lane == 63) wsum[w] = x;
    __syncthreads();
    if (t == 0) { int run = 0; for (int k = 0; k < 4; ++k) { int tmp = wsum[k]; wsum[k] = run; run += tmp; } }
    __syncthreads();
    int excl = wsum[w] + x - s;
    cnt[2 * t] = excl; cnt[2 * t + 1] = excl + v0;
    cur[2 * t] = excl; cur[2 * t + 1] = excl + v0;
    if (2 * t < nb)     rowptr[node0 + 2 * t]     = beg + excl;
    if (2 * t + 1 < nb) rowptr[node0 + 2 * t + 1] = beg + excl + v0;
    __syncthreads();
    for (int i = beg + t; i < end; i += 256) {
        uint2 e = ebuf[i];
        int pos = beg + atomicAdd(&cur[e.y & 511], 1);
        ssrc[pos] = (int)e.x;
    }
}

// ---------- fused per-node GAT aggregate: exact 2-pass softmax, bf16 hp gather ----------
__device__ __forceinline__ float lrelu(float v) { return v > 0.f ? v : SLOPE * v; }

#define WPB 4   // waves (nodes) per block
__global__ __launch_bounds__(256) void gat_gather(
    const int* __restrict__ rowptr, const int* __restrict__ ssrc,
    const float* __restrict__ asrc, const float* __restrict__ adst,
    const ushortT* __restrict__ hpb, const float* __restrict__ bias,
    float* __restrict__ foutF, ushortT* __restrict__ foutB)
{
    __shared__ float s_exp[WPB][64][4];
    __shared__ int   s_src[WPB][64];
    int w = threadIdx.x >> 6;
    int lane = threadIdx.x & 63;
    int node = blockIdx.x * WPB + w;
    if (node >= N_NODES) return;
    int beg = rowptr[node];
    int deg = rowptr[node + 1] - beg;
    float4 ad = *(const float4*)(adst + (size_t)node * 4);

    // ---- phase A: max only ----
    float4 m = make_float4(-1e30f, -1e30f, -1e30f, -1e30f);
    for (int i = lane; i < deg; i += 64) {
        int s = ssrc[beg + i];
        float4 a = *(const float4*)(asrc + (size_t)s * 4);
        m.x = fmaxf(m.x, lrelu(a.x + ad.x));
        m.y = fmaxf(m.y, lrelu(a.y + ad.y));
        m.z = fmaxf(m.z, lrelu(a.z + ad.z));
        m.w = fmaxf(m.w, lrelu(a.w + ad.w));
    }
#pragma unroll
    for (int off = 1; off < 64; off <<= 1) {
        m.x = fmaxf(m.x, __shfl_xor(m.x, off));
        m.y = fmaxf(m.y, __shfl_xor(m.y, off));
        m.z = fmaxf(m.z, __shfl_xor(m.z, off));
        m.w = fmaxf(m.w, __shfl_xor(m.w, off));
    }
    int head = lane >> 4;   // lane owns channels {2*lane, 2*lane+1}

    // ---- phase C: exp once per edge, unnormalized msg + z ----
    float acc0 = 0.f, acc1 = 0.f;
    float4 zp = make_float4(0.f, 0.f, 0.f, 0.f);
    const ushortT* hrow = hpb + lane * 2;
    for (int c0 = 0; c0 < deg; c0 += 64) {
        int n_ch = min(64, deg - c0);
        if (lane < n_ch) {
            int s = ssrc[beg + c0 + lane];
            float4 a = *(const float4*)(asrc + (size_t)s * 4);
            float4 ex;
            ex.x = expf(lrelu(a.x + ad.x) - m.x);
            ex.y = expf(lrelu(a.y + ad.y) - m.y);
            ex.z = expf(lrelu(a.z + ad.z) - m.z);
            ex.w = expf(lrelu(a.w + ad.w) - m.w);
            *(float4*)&s_exp[w][lane][0] = ex;
            s_src[w][lane] = s;
            zp.x += ex.x; zp.y += ex.y; zp.z += ex.z; zp.w += ex.w;
        }
        asm volatile("s_waitcnt lgkmcnt(0)" ::: "memory");
#pragma unroll 4
        for (int i = 0; i < n_ch; ++i) {
            float e = s_exp[w][i][head];
            int s = s_src[w][i];
            uintT u = *(const uintT*)(hrow + (size_t)s * HC);
            float h0 = __uint_as_float(u << 16);
            float h1 = __uint_as_float(u & 0xffff0000u);
            acc0 = fmaf(h0, e, acc0);
            acc1 = fmaf(h1, e, acc1);
        }
    }
#pragma unroll
    for (int off = 1; off < 64; off <<= 1) {
        zp.x += __shfl_xor(zp.x, off);
        zp.y += __shfl_xor(zp.y, off);
        zp.z += __shfl_xor(zp.z, off);
        zp.w += __shfl_xor(zp.w, off);
    }
    float zh = (head == 0) ? zp.x : (head == 1) ? zp.y : (head == 2) ? zp.z : zp.w;
    float zinv = 1.f / zh;
    float b0 = bias[lane * 2], b1 = bias[lane * 2 + 1];
    float v0 = acc0 * zinv + b0; v0 = v0 > 0.f ? v0 : expm1f(v0);
    float v1 = acc1 * zinv + b1; v1 = v1 > 0.f ? v1 : expm1f(v1);
    if (foutF) *(float2*)(foutF + (size_t)node * HC + lane * 2) = make_float2(v0, v1);
    if (foutB) *(uintT*)(foutB + (size_t)node * HC + lane * 2) =
        (uintT)f2bu(v0) | ((uintT)f2bu(v1) << 16);
}

// ---------- fused classifier GEMM + log_softmax ----------
__global__ void cls_logsoftmax(const float* __restrict__ h, const float* __restrict__ Wout,
                               float* __restrict__ out) {
    int row = blockIdx.x;
    __shared__ float hs[HC];
    int t = threadIdx.x;  // 64 threads = 1 wave
    hs[t] = h[(size_t)row * HC + t];
    hs[t + 64] = h[(size_t)row * HC + 64 + t];
    __syncthreads();
    float acc = 0.f;
    if (t < CLASSES) {
#pragma unroll
        for (int k = 0; k < HC; ++k) acc = fmaf(hs[k], Wout[k * CLASSES + t], acc);
    }
    float v = (t < CLASSES) ? acc : -1e30f;
#pragma unroll
    for (int off = 32; off; off >>= 1) v = fmaxf(v, __shfl_xor(v, off));
    float m = v;
    float ex = (t < CLASSES) ? expf(acc - m) : 0.f;
#pragma unroll
    for (int off = 32; off; off >>= 1) ex += __shfl_xor(ex, off);
    float ls = logf(ex);
    if (t < CLASSES) out[(size_t)row * CLASSES + t] = acc - m - ls;
}

extern "C" void kernel_launch(void* const* d_in, const int* in_sizes, int n_in,
                              void* d_out, int out_size, void* d_ws, size_t ws_size,
                              hipStream_t stream) {
    const float* x      = (const float*)d_in[0];
    const int*   ei     = (const int*)d_in[1];
    const float* w_in   = (const float*)d_in[2];
    const float* Ws     = (const float*)d_in[3];
    const float* atts   = (const float*)d_in[4];
    const float* biases = (const float*)d_in[5];
    const float* w_out  = (const float*)d_in[6];
    float* out = (float*)d_out;

    // workspace partition
    char* wp = (char*)d_ws;
    ushortT* hb0 = (ushortT*)wp; wp += (size_t)N_NODES * HC * 2;   // bf16 h (G0 out)
    ushortT* hb1 = (ushortT*)wp; wp += (size_t)N_NODES * HC * 2;   // bf16 gat_l0 out
    float* hpf   = (float*)wp;   wp += (size_t)N_NODES * HC * 4;   // fp32 hp
    ushortT* hpb = (ushortT*)wp; wp += (size_t)N_NODES * HC * 2;   // bf16 hp
    float* hf    = (float*)wp;   wp += (size_t)N_NODES * HC * 4;   // fp32 gat_l1 out
    float* asrc  = (float*)wp;   wp += (size_t)N_NODES * HEADS * 4;
    float* adst  = (float*)wp;   wp += (size_t)N_NODES * HEADS * 4;
    int* rowptr  = (int*)wp;     wp += (size_t)(N_NODES + 4) * 4;
    int* ssrc    = (int*)wp;     wp += (size_t)EE * 4;
    uint2* ebuf  = (uint2*)wp;   wp += (size_t)EE * 8;
    int* bcnt    = (int*)wp;     wp += (size_t)(NBUCK + 4) * 4;
    int* bbase   = (int*)wp;     wp += (size_t)(NBUCK + 4) * 4;
    int* gcur    = (int*)wp;     wp += (size_t)(NBUCK + 4) * 4;
    ushortT* w_inT = (ushortT*)wp; wp += (size_t)HC * F_IN * 2;
    ushortT* WsT   = (ushortT*)wp; wp += (size_t)LAYERS * HC * HC * 2;

    // ---- CSR build: two-level bucket sort ----
    hipMemsetAsync(bcnt, 0, (size_t)NBUCK * 4, stream);
    bucket_count<<<NBLK_E, 256, 0, stream>>>(ei, bcnt);
    bucket_scan<<<1, 64, 0, stream>>>(bcnt, bbase, gcur, rowptr);
    bucket_scatter<<<NBLK_E, 256, 0, stream>>>(ei, gcur, ebuf);
    csr_local<<<NBUCK, 256, 0, stream>>>(ebuf, bbase, rowptr, ssrc);

    // ---- weight convert+transpose ----
    wconv<<<(F_IN * HC + 255) / 256, 256, 0, stream>>>(w_in, w_inT, F_IN);
    wconv<<<(HC * HC + 255) / 256, 256, 0, stream>>>(Ws, WsT, HC);
    wconv<<<(HC * HC + 255) / 256, 256, 0, stream>>>(Ws + (size_t)HC * HC, WsT + (size_t)HC * HC, HC);

    int gblk = (N_NODES + 63) / 64;
    // h = x @ w_in  -> bf16 only
    gemm_mfma<true><<<gblk, 256, 0, stream>>>(x, w_inT, (float*)nullptr, hb0, N_NODES, F_IN);

    const ushortT* hin_b = hb0;
    for (int l = 0; l < LAYERS; ++l) {
        gemm_mfma<false><<<gblk, 256, 0, stream>>>(hin_b, WsT + (size_t)l * HC * HC,
                                                   hpf, hpb, N_NODES, HC);
        node_alpha<<<(N_NODES * HEADS + 255) / 256, 256, 0, stream>>>(
            hpf, atts + (size_t)l * HEADS * 2 * HID, asrc, adst);
        gat_gather<<<(N_NODES + WPB - 1) / WPB, 64 * WPB, 0, stream>>>(
            rowptr, ssrc, asrc, adst, hpb, biases + (size_t)l * HC,
            (l == LAYERS - 1) ? hf : (float*)nullptr,
            (l == LAYERS - 1) ? (ushortT*)nullptr : hb1);
        hin_b = hb1;
    }

    cls_logsoftmax<<<N_NODES, 64, 0, stream>>>(hf, w_out, out);
}

// Round 7
// 228.585 us; speedup vs baseline: 17.2220x; 1.1978x over previous
//
#include <hip/hip_runtime.h>
#include <hip/hip_bf16.h>
#include <math.h>

#define N_NODES 50000
#define N_EDGES 800000
#define F_IN 256
#define HID 32
#define HEADS 4
#define HC 128            // HID*HEADS
#define CLASSES 40
#define LAYERS 2
#define SLOPE 0.1f
#define EE (N_EDGES + N_NODES)   // edges + self loops

#define BSHIFT 9
#define NBUCK 98          // ceil(50000 / 512)
#define CHUNK 4096        // edges per block in bucket passes
#define NBLK_E ((EE + CHUNK - 1) / CHUNK)

typedef unsigned short ushortT;
typedef unsigned int uintT;
typedef __attribute__((ext_vector_type(8))) short short8v;   // 8 bf16 = 4 VGPRs
typedef __attribute__((ext_vector_type(4))) float f32x4;

__device__ __forceinline__ ushortT f2bu(float f) {
    __hip_bfloat16 h = __float2bfloat16(f);
    ushortT u; __builtin_memcpy(&u, &h, 2); return u;
}

// ---------- weight transpose+convert: W[K][128] fp32 -> WT[128][K] bf16 ----------
__global__ void wconv(const float* __restrict__ W, ushortT* __restrict__ WT, int K) {
    int i = blockIdx.x * 256 + threadIdx.x;
    if (i >= K * 128) return;
    int r = i >> 7, c = i & 127;
    WT[(size_t)c * K + r] = f2bu(W[i]);
}

// Wout[128][40] fp32 -> WT[48][128] bf16, cols 40..47 zero
__global__ void wconv_cls(const float* __restrict__ W, ushortT* __restrict__ WT) {
    int i = blockIdx.x * 256 + threadIdx.x;
    if (i >= 48 * 128) return;
    int c = i >> 7, k = i & 127;
    WT[i] = (c < CLASSES) ? f2bu(W[k * CLASSES + c]) : (ushortT)0;
}

// ---------- MFMA bf16 GEMM, N fixed 128 ----------
#define AS_LD 40
template<bool AF32>
__global__ __launch_bounds__(256) void gemm_mfma(const void* __restrict__ Aptr,
                                                 const ushortT* __restrict__ BT,
                                                 float* __restrict__ Cf,      // may be null
                                                 ushortT* __restrict__ Cb,    // may be null
                                                 int M, int K) {
    __shared__ ushortT As[64 * AS_LD];    // [row][k<32]
    __shared__ ushortT Bs[128 * AS_LD];   // [col][k<32]
    int t = threadIdx.x;
    int w = t >> 6, lane = t & 63;
    int row0 = blockIdx.x * 64;
    int ar = t >> 2, ak = (t & 3) * 8;
    int bcol = t >> 1, bks = (t & 1) * 16;
    int wr = w * 16;
    int arow = wr + (lane & 15);
    int ak8 = (lane >> 4) * 8;
    f32x4 acc[8] = {};

    for (int k0 = 0; k0 < K; k0 += 32) {
        int grow = row0 + ar;
        if (AF32) {
            const float* A = (const float*)Aptr;
            float4 v0 = make_float4(0.f, 0.f, 0.f, 0.f), v1 = v0;
            if (grow < M) {
                const float* ap = A + (size_t)grow * K + k0 + ak;
                v0 = *(const float4*)ap;
                v1 = *(const float4*)(ap + 4);
            }
            uint4 p;
            p.x = (uintT)f2bu(v0.x) | ((uintT)f2bu(v0.y) << 16);
            p.y = (uintT)f2bu(v0.z) | ((uintT)f2bu(v0.w) << 16);
            p.z = (uintT)f2bu(v1.x) | ((uintT)f2bu(v1.y) << 16);
            p.w = (uintT)f2bu(v1.z) | ((uintT)f2bu(v1.w) << 16);
            *(uint4*)&As[ar * AS_LD + ak] = p;
        } else {
            const ushortT* A = (const ushortT*)Aptr;
            uint4 p = make_uint4(0, 0, 0, 0);
            if (grow < M) p = *(const uint4*)(A + (size_t)grow * K + k0 + ak);
            *(uint4*)&As[ar * AS_LD + ak] = p;
        }
        {
            const ushortT* bp = BT + (size_t)bcol * K + k0 + bks;
            *(uint4*)&Bs[bcol * AS_LD + bks]     = *(const uint4*)bp;
            *(uint4*)&Bs[bcol * AS_LD + bks + 8] = *(const uint4*)(bp + 8);
        }
        __syncthreads();
        short8v a = *(short8v*)&As[arow * AS_LD + ak8];
#pragma unroll
        for (int c = 0; c < 8; ++c) {
            short8v b = *(short8v*)&Bs[(c * 16 + (lane & 15)) * AS_LD + ak8];
            acc[c] = __builtin_amdgcn_mfma_f32_16x16x32_bf16(a, b, acc[c], 0, 0, 0);
        }
        __syncthreads();
    }
    int r0 = row0 + wr + ((lane >> 4) << 2);
    int col = lane & 15;
#pragma unroll
    for (int c = 0; c < 8; ++c) {
        int cc = c * 16 + col;
#pragma unroll
        for (int r = 0; r < 4; ++r) {
            int rr = r0 + r;
            if (rr < M) {
                if (Cf) Cf[(size_t)rr * 128 + cc] = acc[c][r];
                if (Cb) Cb[(size_t)rr * 128 + cc] = f2bu(acc[c][r]);
            }
        }
    }
}

// ---------- fused MFMA classifier + in-register log_softmax ----------
// C[M,40] = A[M,128](bf16) @ WoutT[48][128](bf16, cols40..47=0); row log-softmax.
__global__ __launch_bounds__(256) void cls_mfma(const ushortT* __restrict__ A,
                                                const ushortT* __restrict__ BT,
                                                float* __restrict__ out, int M) {
    __shared__ ushortT As[64 * AS_LD];
    __shared__ ushortT Bs[48 * AS_LD];
    int t = threadIdx.x;
    int w = t >> 6, lane = t & 63;
    int row0 = blockIdx.x * 64;
    int ar = t >> 2, ak = (t & 3) * 8;
    int wr = w * 16;
    int arow = wr + (lane & 15);
    int ak8 = (lane >> 4) * 8;
    f32x4 acc[3] = {};

    for (int k0 = 0; k0 < 128; k0 += 32) {
        int grow = row0 + ar;
        uint4 p = make_uint4(0, 0, 0, 0);
        if (grow < M) p = *(const uint4*)(A + (size_t)grow * 128 + k0 + ak);
        *(uint4*)&As[ar * AS_LD + ak] = p;
        if (t < 96) {
            int bcol = t >> 1, bks = (t & 1) * 16;
            const ushortT* bp = BT + bcol * 128 + k0 + bks;
            *(uint4*)&Bs[bcol * AS_LD + bks]     = *(const uint4*)bp;
            *(uint4*)&Bs[bcol * AS_LD + bks + 8] = *(const uint4*)(bp + 8);
        }
        __syncthreads();
        short8v a = *(short8v*)&As[arow * AS_LD + ak8];
#pragma unroll
        for (int c = 0; c < 3; ++c) {
            short8v b = *(short8v*)&Bs[(c * 16 + (lane & 15)) * AS_LD + ak8];
            acc[c] = __builtin_amdgcn_mfma_f32_16x16x32_bf16(a, b, acc[c], 0, 0, 0);
        }
        __syncthreads();
    }
    int cl = lane & 15;
    int r0 = row0 + wr + ((lane >> 4) << 2);
#pragma unroll
    for (int r = 0; r < 4; ++r) {
        float v0 = acc[0][r], v1 = acc[1][r];
        float v2 = (cl < 8) ? acc[2][r] : -1e30f;
        float m = fmaxf(fmaxf(v0, v1), v2);
#pragma unroll
        for (int off = 1; off < 16; off <<= 1) m = fmaxf(m, __shfl_xor(m, off));
        float e = expf(v0 - m) + expf(v1 - m) + ((cl < 8) ? expf(v2 - m) : 0.f);
#pragma unroll
        for (int off = 1; off < 16; off <<= 1) e += __shfl_xor(e, off);
        float ls = m + logf(e);
        int rr = r0 + r;
        if (rr < M) {
            float* o = out + (size_t)rr * CLASSES;
            o[cl] = v0 - ls;
            o[16 + cl] = v1 - ls;
            if (cl < 8) o[32 + cl] = v2 - ls;
        }
    }
}

// ---------- per-node attention coefficients (bf16 hp) ----------
__global__ void node_alpha(const ushortT* __restrict__ hpb, const float* __restrict__ att,
                           float* __restrict__ asrc, float* __restrict__ adst) {
    int t = blockIdx.x * blockDim.x + threadIdx.x;  // n*HEADS + h
    if (t >= N_NODES * HEADS) return;
    int n = t >> 2, h = t & 3;
    const uintT* v = (const uintT*)(hpb + (size_t)n * HC + h * HID);  // 16 uints = 32 bf16
    const float* as = att + h * 2 * HID;
    const float* ad = as + HID;
    float s = 0.f, d = 0.f;
#pragma unroll
    for (int c = 0; c < 16; ++c) {
        uintT u = v[c];
        float x0 = __uint_as_float(u << 16);
        float x1 = __uint_as_float(u & 0xffff0000u);
        s = fmaf(x0, as[2 * c], s); s = fmaf(x1, as[2 * c + 1], s);
        d = fmaf(x0, ad[2 * c], d); d = fmaf(x1, ad[2 * c + 1], d);
    }
    asrc[t] = s;
    adst[t] = d;
}

// ---------- CSR build via two-level bucket sort ----------
__global__ __launch_bounds__(256) void bucket_count(const int* __restrict__ ei,
                                                    int* __restrict__ bcnt) {
    __shared__ int hist[NBUCK];
    int t = threadIdx.x;
    if (t < NBUCK) hist[t] = 0;
    __syncthreads();
    int base = blockIdx.x * CHUNK;
    int end = min(base + CHUNK, EE);
    for (int i = base + t; i < end; i += 256) {
        int d = (i < N_EDGES) ? ei[N_EDGES + i] : (i - N_EDGES);
        atomicAdd(&hist[d >> BSHIFT], 1);
    }
    __syncthreads();
    if (t < NBUCK && hist[t]) atomicAdd(&bcnt[t], hist[t]);
}

__global__ void bucket_scan(const int* __restrict__ bcnt, int* __restrict__ bbase,
                            int* __restrict__ gcur, int* __restrict__ rowptr) {
    if (threadIdx.x == 0) {
        int run = 0;
        for (int b = 0; b < NBUCK; ++b) { bbase[b] = run; gcur[b] = run; run += bcnt[b]; }
        bbase[NBUCK] = run;
        rowptr[N_NODES] = run;   // == EE
    }
}

__global__ __launch_bounds__(256) void bucket_scatter(const int* __restrict__ ei,
                                                      int* __restrict__ gcur,
                                                      uint2* __restrict__ ebuf) {
    __shared__ int hist[NBUCK];
    __shared__ int rbase[NBUCK];
    int t = threadIdx.x;
    if (t < NBUCK) hist[t] = 0;
    __syncthreads();
    int base = blockIdx.x * CHUNK;
    int end = min(base + CHUNK, EE);
    for (int i = base + t; i < end; i += 256) {
        int d = (i < N_EDGES) ? ei[N_EDGES + i] : (i - N_EDGES);
        atomicAdd(&hist[d >> BSHIFT], 1);
    }
    __syncthreads();
    if (t < NBUCK) {
        int c = hist[t];
        rbase[t] = c ? atomicAdd(&gcur[t], c) : 0;
    }
    __syncthreads();
    if (t < NBUCK) hist[t] = 0;
    __syncthreads();
    for (int i = base + t; i < end; i += 256) {
        int s, d;
        if (i < N_EDGES) { s = ei[i]; d = ei[N_EDGES + i]; } else { s = d = i - N_EDGES; }
        int b = d >> BSHIFT;
        int pos = rbase[b] + atomicAdd(&hist[b], 1);
        ebuf[pos] = make_uint2((uintT)s, (uintT)d);
    }
}

__global__ __launch_bounds__(256) void csr_local(const uint2* __restrict__ ebuf,
                                                 const int* __restrict__ bbase,
                                                 int* __restrict__ rowptr,
                                                 int* __restrict__ ssrc) {
    __shared__ int cnt[512];
    __shared__ int cur[512];
    __shared__ int wsum[4];
    int b = blockIdx.x;
    int t = threadIdx.x;
    int node0 = b << BSHIFT;
    int nb = min(512, N_NODES - node0);
    int beg = bbase[b], end = bbase[b + 1];
    cnt[t] = 0; cnt[t + 256] = 0;
    __syncthreads();
    for (int i = beg + t; i < end; i += 256)
        atomicAdd(&cnt[ebuf[i].y & 511], 1);
    __syncthreads();
    int v0 = cnt[2 * t], v1 = cnt[2 * t + 1];
    int s = v0 + v1;
    int lane = t & 63, w = t >> 6;
    int x = s;
#pragma unroll
    for (int off = 1; off < 64; off <<= 1) { int y = __shfl_up(x, off); if (lane >= off) x += y; }
    if (lane == 63) wsum[w] = x;
    __syncthreads();
    if (t == 0) { int run = 0; for (int k = 0; k < 4; ++k) { int tmp = wsum[k]; wsum[k] = run; run += tmp; } }
    __syncthreads();
    int excl = wsum[w] + x - s;
    cnt[2 * t] = excl; cnt[2 * t + 1] = excl + v0;
    cur[2 * t] = excl; cur[2 * t + 1] = excl + v0;
    if (2 * t < nb)     rowptr[node0 + 2 * t]     = beg + excl;
    if (2 * t + 1 < nb) rowptr[node0 + 2 * t + 1] = beg + excl + v0;
    __syncthreads();
    for (int i = beg + t; i < end; i += 256) {
        uint2 e = ebuf[i];
        int pos = beg + atomicAdd(&cur[e.y & 511], 1);
        ssrc[pos] = (int)e.x;
    }
}

// ---------- fused per-node GAT aggregate: exact 2-pass softmax, bf16 in/out ----------
__device__ __forceinline__ float lrelu(float v) { return v > 0.f ? v : SLOPE * v; }

#define WPB 4   // waves (nodes) per block
__global__ __launch_bounds__(256) void gat_gather(
    const int* __restrict__ rowptr, const int* __restrict__ ssrc,
    const float* __restrict__ asrc, const float* __restrict__ adst,
    const ushortT* __restrict__ hpb, const float* __restrict__ bias,
    ushortT* __restrict__ foutB)
{
    __shared__ float s_exp[WPB][64][4];
    __shared__ int   s_src[WPB][64];
    int w = threadIdx.x >> 6;
    int lane = threadIdx.x & 63;
    int node = blockIdx.x * WPB + w;
    if (node >= N_NODES) return;
    int beg = rowptr[node];
    int deg = rowptr[node + 1] - beg;
    float4 ad = *(const float4*)(adst + (size_t)node * 4);

    // ---- phase A: max only ----
    float4 m = make_float4(-1e30f, -1e30f, -1e30f, -1e30f);
    for (int i = lane; i < deg; i += 64) {
        int s = ssrc[beg + i];
        float4 a = *(const float4*)(asrc + (size_t)s * 4);
        m.x = fmaxf(m.x, lrelu(a.x + ad.x));
        m.y = fmaxf(m.y, lrelu(a.y + ad.y));
        m.z = fmaxf(m.z, lrelu(a.z + ad.z));
        m.w = fmaxf(m.w, lrelu(a.w + ad.w));
    }
#pragma unroll
    for (int off = 1; off < 64; off <<= 1) {
        m.x = fmaxf(m.x, __shfl_xor(m.x, off));
        m.y = fmaxf(m.y, __shfl_xor(m.y, off));
        m.z = fmaxf(m.z, __shfl_xor(m.z, off));
        m.w = fmaxf(m.w, __shfl_xor(m.w, off));
    }
    int head = lane >> 4;   // lane owns channels {2*lane, 2*lane+1}

    // ---- phase C: exp once per edge, unnormalized msg + z ----
    float acc0 = 0.f, acc1 = 0.f;
    float4 zp = make_float4(0.f, 0.f, 0.f, 0.f);
    const ushortT* hrow = hpb + lane * 2;
    for (int c0 = 0; c0 < deg; c0 += 64) {
        int n_ch = min(64, deg - c0);
        if (lane < n_ch) {
            int s = ssrc[beg + c0 + lane];
            float4 a = *(const float4*)(asrc + (size_t)s * 4);
            float4 ex;
            ex.x = expf(lrelu(a.x + ad.x) - m.x);
            ex.y = expf(lrelu(a.y + ad.y) - m.y);
            ex.z = expf(lrelu(a.z + ad.z) - m.z);
            ex.w = expf(lrelu(a.w + ad.w) - m.w);
            *(float4*)&s_exp[w][lane][0] = ex;
            s_src[w][lane] = s;
            zp.x += ex.x; zp.y += ex.y; zp.z += ex.z; zp.w += ex.w;
        }
        asm volatile("s_waitcnt lgkmcnt(0)" ::: "memory");
#pragma unroll 4
        for (int i = 0; i < n_ch; ++i) {
            float e = s_exp[w][i][head];
            int s = s_src[w][i];
            uintT u = *(const uintT*)(hrow + (size_t)s * HC);
            float h0 = __uint_as_float(u << 16);
            float h1 = __uint_as_float(u & 0xffff0000u);
            acc0 = fmaf(h0, e, acc0);
            acc1 = fmaf(h1, e, acc1);
        }
    }
#pragma unroll
    for (int off = 1; off < 64; off <<= 1) {
        zp.x += __shfl_xor(zp.x, off);
        zp.y += __shfl_xor(zp.y, off);
        zp.z += __shfl_xor(zp.z, off);
        zp.w += __shfl_xor(zp.w, off);
    }
    float zh = (head == 0) ? zp.x : (head == 1) ? zp.y : (head == 2) ? zp.z : zp.w;
    float zinv = 1.f / zh;
    float b0 = bias[lane * 2], b1 = bias[lane * 2 + 1];
    float v0 = acc0 * zinv + b0; v0 = v0 > 0.f ? v0 : expm1f(v0);
    float v1 = acc1 * zinv + b1; v1 = v1 > 0.f ? v1 : expm1f(v1);
    *(uintT*)(foutB + (size_t)node * HC + lane * 2) =
        (uintT)f2bu(v0) | ((uintT)f2bu(v1) << 16);
}

extern "C" void kernel_launch(void* const* d_in, const int* in_sizes, int n_in,
                              void* d_out, int out_size, void* d_ws, size_t ws_size,
                              hipStream_t stream) {
    const float* x      = (const float*)d_in[0];
    const int*   ei     = (const int*)d_in[1];
    const float* w_in   = (const float*)d_in[2];
    const float* Ws     = (const float*)d_in[3];
    const float* atts   = (const float*)d_in[4];
    const float* biases = (const float*)d_in[5];
    const float* w_out  = (const float*)d_in[6];
    float* out = (float*)d_out;

    // workspace partition
    char* wp = (char*)d_ws;
    ushortT* hb0 = (ushortT*)wp; wp += (size_t)N_NODES * HC * 2;   // bf16 h / final gat out
    ushortT* hb1 = (ushortT*)wp; wp += (size_t)N_NODES * HC * 2;   // bf16 gat_l0 out
    ushortT* hpb = (ushortT*)wp; wp += (size_t)N_NODES * HC * 2;   // bf16 hp
    float* asrc  = (float*)wp;   wp += (size_t)N_NODES * HEADS * 4;
    float* adst  = (float*)wp;   wp += (size_t)N_NODES * HEADS * 4;
    int* rowptr  = (int*)wp;     wp += (size_t)(N_NODES + 4) * 4;
    int* ssrc    = (int*)wp;     wp += (size_t)EE * 4;
    uint2* ebuf  = (uint2*)wp;   wp += (size_t)EE * 8;
    int* bcnt    = (int*)wp;     wp += (size_t)(NBUCK + 4) * 4;
    int* bbase   = (int*)wp;     wp += (size_t)(NBUCK + 4) * 4;
    int* gcur    = (int*)wp;     wp += (size_t)(NBUCK + 4) * 4;
    ushortT* w_inT = (ushortT*)wp; wp += (size_t)HC * F_IN * 2;
    ushortT* WsT   = (ushortT*)wp; wp += (size_t)LAYERS * HC * HC * 2;
    ushortT* woutT = (ushortT*)wp; wp += (size_t)48 * HC * 2;

    // ---- CSR build: two-level bucket sort ----
    hipMemsetAsync(bcnt, 0, (size_t)NBUCK * 4, stream);
    bucket_count<<<NBLK_E, 256, 0, stream>>>(ei, bcnt);
    bucket_scan<<<1, 64, 0, stream>>>(bcnt, bbase, gcur, rowptr);
    bucket_scatter<<<NBLK_E, 256, 0, stream>>>(ei, gcur, ebuf);
    csr_local<<<NBUCK, 256, 0, stream>>>(ebuf, bbase, rowptr, ssrc);

    // ---- weight convert+transpose ----
    wconv<<<(F_IN * HC + 255) / 256, 256, 0, stream>>>(w_in, w_inT, F_IN);
    wconv<<<(HC * HC + 255) / 256, 256, 0, stream>>>(Ws, WsT, HC);
    wconv<<<(HC * HC + 255) / 256, 256, 0, stream>>>(Ws + (size_t)HC * HC, WsT + (size_t)HC * HC, HC);
    wconv_cls<<<(48 * HC + 255) / 256, 256, 0, stream>>>(w_out, woutT);

    int gblk = (N_NODES + 63) / 64;
    // h = x @ w_in  -> bf16 only
    gemm_mfma<true><<<gblk, 256, 0, stream>>>(x, w_inT, (float*)nullptr, hb0, N_NODES, F_IN);

    const ushortT* hin_b = hb0;
    ushortT* gout[LAYERS] = { hb1, hb0 };
    for (int l = 0; l < LAYERS; ++l) {
        gemm_mfma<false><<<gblk, 256, 0, stream>>>(hin_b, WsT + (size_t)l * HC * HC,
                                                   (float*)nullptr, hpb, N_NODES, HC);
        node_alpha<<<(N_NODES * HEADS + 255) / 256, 256, 0, stream>>>(
            hpb, atts + (size_t)l * HEADS * 2 * HID, asrc, adst);
        gat_gather<<<(N_NODES + WPB - 1) / WPB, 64 * WPB, 0, stream>>>(
            rowptr, ssrc, asrc, adst, hpb, biases + (size_t)l * HC, gout[l]);
        hin_b = gout[l];
    }

    cls_mfma<<<gblk, 256, 0, stream>>>(hb0, woutT, out, N_NODES);
}

// Round 8
// 212.346 us; speedup vs baseline: 18.5390x; 1.0765x over previous
//
#include <hip/hip_runtime.h>
#include <hip/hip_bf16.h>
#include <math.h>

#define N_NODES 50000
#define N_EDGES 800000
#define F_IN 256
#define HID 32
#define HEADS 4
#define HC 128            // HID*HEADS
#define CLASSES 40
#define LAYERS 2
#define SLOPE 0.1f
#define EE (N_EDGES + N_NODES)   // edges + self loops

#define BSHIFT 9
#define NBUCK 98          // ceil(50000 / 512)
#define CHUNK 4096        // edges per block in bucket passes
#define NBLK_E ((EE + CHUNK - 1) / CHUNK)

typedef unsigned short ushortT;
typedef unsigned int uintT;
typedef __attribute__((ext_vector_type(8))) short short8v;   // 8 bf16 = 4 VGPRs
typedef __attribute__((ext_vector_type(4))) float f32x4;

__device__ __forceinline__ ushortT f2bu(float f) {
    __hip_bfloat16 h = __float2bfloat16(f);
    ushortT u; __builtin_memcpy(&u, &h, 2); return u;
}

// ---------- weight transpose+convert: W[K][128] fp32 -> WT[128][K] bf16 ----------
__global__ void wconv(const float* __restrict__ W, ushortT* __restrict__ WT, int K) {
    int i = blockIdx.x * 256 + threadIdx.x;
    if (i >= K * 128) return;
    int r = i >> 7, c = i & 127;
    WT[(size_t)c * K + r] = f2bu(W[i]);
}

// Wout[128][40] fp32 -> WT[48][128] bf16, cols 40..47 zero
__global__ void wconv_cls(const float* __restrict__ W, ushortT* __restrict__ WT) {
    int i = blockIdx.x * 256 + threadIdx.x;
    if (i >= 48 * 128) return;
    int c = i >> 7, k = i & 127;
    WT[i] = (c < CLASSES) ? f2bu(W[k * CLASSES + c]) : (ushortT)0;
}

// ---------- MFMA bf16 GEMM, N fixed 128 ----------
#define AS_LD 40
template<bool AF32>
__global__ __launch_bounds__(256) void gemm_mfma(const void* __restrict__ Aptr,
                                                 const ushortT* __restrict__ BT,
                                                 float* __restrict__ Cf,      // may be null
                                                 ushortT* __restrict__ Cb,    // may be null
                                                 int M, int K) {
    __shared__ ushortT As[64 * AS_LD];    // [row][k<32]
    __shared__ ushortT Bs[128 * AS_LD];   // [col][k<32]
    int t = threadIdx.x;
    int w = t >> 6, lane = t & 63;
    int row0 = blockIdx.x * 64;
    int ar = t >> 2, ak = (t & 3) * 8;
    int bcol = t >> 1, bks = (t & 1) * 16;
    int wr = w * 16;
    int arow = wr + (lane & 15);
    int ak8 = (lane >> 4) * 8;
    f32x4 acc[8] = {};

    for (int k0 = 0; k0 < K; k0 += 32) {
        int grow = row0 + ar;
        if (AF32) {
            const float* A = (const float*)Aptr;
            float4 v0 = make_float4(0.f, 0.f, 0.f, 0.f), v1 = v0;
            if (grow < M) {
                const float* ap = A + (size_t)grow * K + k0 + ak;
                v0 = *(const float4*)ap;
                v1 = *(const float4*)(ap + 4);
            }
            uint4 p;
            p.x = (uintT)f2bu(v0.x) | ((uintT)f2bu(v0.y) << 16);
            p.y = (uintT)f2bu(v0.z) | ((uintT)f2bu(v0.w) << 16);
            p.z = (uintT)f2bu(v1.x) | ((uintT)f2bu(v1.y) << 16);
            p.w = (uintT)f2bu(v1.z) | ((uintT)f2bu(v1.w) << 16);
            *(uint4*)&As[ar * AS_LD + ak] = p;
        } else {
            const ushortT* A = (const ushortT*)Aptr;
            uint4 p = make_uint4(0, 0, 0, 0);
            if (grow < M) p = *(const uint4*)(A + (size_t)grow * K + k0 + ak);
            *(uint4*)&As[ar * AS_LD + ak] = p;
        }
        {
            const ushortT* bp = BT + (size_t)bcol * K + k0 + bks;
            *(uint4*)&Bs[bcol * AS_LD + bks]     = *(const uint4*)bp;
            *(uint4*)&Bs[bcol * AS_LD + bks + 8] = *(const uint4*)(bp + 8);
        }
        __syncthreads();
        short8v a = *(short8v*)&As[arow * AS_LD + ak8];
#pragma unroll
        for (int c = 0; c < 8; ++c) {
            short8v b = *(short8v*)&Bs[(c * 16 + (lane & 15)) * AS_LD + ak8];
            acc[c] = __builtin_amdgcn_mfma_f32_16x16x32_bf16(a, b, acc[c], 0, 0, 0);
        }
        __syncthreads();
    }
    int r0 = row0 + wr + ((lane >> 4) << 2);
    int col = lane & 15;
#pragma unroll
    for (int c = 0; c < 8; ++c) {
        int cc = c * 16 + col;
#pragma unroll
        for (int r = 0; r < 4; ++r) {
            int rr = r0 + r;
            if (rr < M) {
                if (Cf) Cf[(size_t)rr * 128 + cc] = acc[c][r];
                if (Cb) Cb[(size_t)rr * 128 + cc] = f2bu(acc[c][r]);
            }
        }
    }
}

// ---------- fused MFMA classifier + in-register log_softmax ----------
__global__ __launch_bounds__(256) void cls_mfma(const ushortT* __restrict__ A,
                                                const ushortT* __restrict__ BT,
                                                float* __restrict__ out, int M) {
    __shared__ ushortT As[64 * AS_LD];
    __shared__ ushortT Bs[48 * AS_LD];
    int t = threadIdx.x;
    int w = t >> 6, lane = t & 63;
    int row0 = blockIdx.x * 64;
    int ar = t >> 2, ak = (t & 3) * 8;
    int wr = w * 16;
    int arow = wr + (lane & 15);
    int ak8 = (lane >> 4) * 8;
    f32x4 acc[3] = {};

    for (int k0 = 0; k0 < 128; k0 += 32) {
        int grow = row0 + ar;
        uint4 p = make_uint4(0, 0, 0, 0);
        if (grow < M) p = *(const uint4*)(A + (size_t)grow * 128 + k0 + ak);
        *(uint4*)&As[ar * AS_LD + ak] = p;
        if (t < 96) {
            int bcol = t >> 1, bks = (t & 1) * 16;
            const ushortT* bp = BT + bcol * 128 + k0 + bks;
            *(uint4*)&Bs[bcol * AS_LD + bks]     = *(const uint4*)bp;
            *(uint4*)&Bs[bcol * AS_LD + bks + 8] = *(const uint4*)(bp + 8);
        }
        __syncthreads();
        short8v a = *(short8v*)&As[arow * AS_LD + ak8];
#pragma unroll
        for (int c = 0; c < 3; ++c) {
            short8v b = *(short8v*)&Bs[(c * 16 + (lane & 15)) * AS_LD + ak8];
            acc[c] = __builtin_amdgcn_mfma_f32_16x16x32_bf16(a, b, acc[c], 0, 0, 0);
        }
        __syncthreads();
    }
    int cl = lane & 15;
    int r0 = row0 + wr + ((lane >> 4) << 2);
#pragma unroll
    for (int r = 0; r < 4; ++r) {
        float v0 = acc[0][r], v1 = acc[1][r];
        float v2 = (cl < 8) ? acc[2][r] : -1e30f;
        float m = fmaxf(fmaxf(v0, v1), v2);
#pragma unroll
        for (int off = 1; off < 16; off <<= 1) m = fmaxf(m, __shfl_xor(m, off));
        float e = __expf(v0 - m) + __expf(v1 - m) + ((cl < 8) ? __expf(v2 - m) : 0.f);
#pragma unroll
        for (int off = 1; off < 16; off <<= 1) e += __shfl_xor(e, off);
        float ls = m + __logf(e);
        int rr = r0 + r;
        if (rr < M) {
            float* o = out + (size_t)rr * CLASSES;
            o[cl] = v0 - ls;
            o[16 + cl] = v1 - ls;
            if (cl < 8) o[32 + cl] = v2 - ls;
        }
    }
}

// ---------- per-node attention coefficients (bf16 hp) ----------
__global__ void node_alpha(const ushortT* __restrict__ hpb, const float* __restrict__ att,
                           float* __restrict__ asrc, float* __restrict__ adst) {
    int t = blockIdx.x * blockDim.x + threadIdx.x;  // n*HEADS + h
    if (t >= N_NODES * HEADS) return;
    int n = t >> 2, h = t & 3;
    const uintT* v = (const uintT*)(hpb + (size_t)n * HC + h * HID);  // 16 uints = 32 bf16
    const float* as = att + h * 2 * HID;
    const float* ad = as + HID;
    float s = 0.f, d = 0.f;
#pragma unroll
    for (int c = 0; c < 16; ++c) {
        uintT u = v[c];
        float x0 = __uint_as_float(u << 16);
        float x1 = __uint_as_float(u & 0xffff0000u);
        s = fmaf(x0, as[2 * c], s); s = fmaf(x1, as[2 * c + 1], s);
        d = fmaf(x0, ad[2 * c], d); d = fmaf(x1, ad[2 * c + 1], d);
    }
    asrc[t] = s;
    adst[t] = d;
}

// ---------- CSR build via two-level bucket sort ----------
__global__ __launch_bounds__(256) void bucket_count(const int* __restrict__ ei,
                                                    int* __restrict__ bcnt) {
    __shared__ int hist[NBUCK];
    int t = threadIdx.x;
    if (t < NBUCK) hist[t] = 0;
    __syncthreads();
    int base = blockIdx.x * CHUNK;
    int end = min(base + CHUNK, EE);
    for (int i = base + t; i < end; i += 256) {
        int d = (i < N_EDGES) ? ei[N_EDGES + i] : (i - N_EDGES);
        atomicAdd(&hist[d >> BSHIFT], 1);
    }
    __syncthreads();
    if (t < NBUCK && hist[t]) atomicAdd(&bcnt[t], hist[t]);
}

__global__ void bucket_scan(const int* __restrict__ bcnt, int* __restrict__ bbase,
                            int* __restrict__ gcur, int* __restrict__ rowptr) {
    if (threadIdx.x == 0) {
        int run = 0;
        for (int b = 0; b < NBUCK; ++b) { bbase[b] = run; gcur[b] = run; run += bcnt[b]; }
        bbase[NBUCK] = run;
        rowptr[N_NODES] = run;   // == EE
    }
}

__global__ __launch_bounds__(256) void bucket_scatter(const int* __restrict__ ei,
                                                      int* __restrict__ gcur,
                                                      uint2* __restrict__ ebuf) {
    __shared__ int hist[NBUCK];
    __shared__ int rbase[NBUCK];
    int t = threadIdx.x;
    if (t < NBUCK) hist[t] = 0;
    __syncthreads();
    int base = blockIdx.x * CHUNK;
    int end = min(base + CHUNK, EE);
    for (int i = base + t; i < end; i += 256) {
        int d = (i < N_EDGES) ? ei[N_EDGES + i] : (i - N_EDGES);
        atomicAdd(&hist[d >> BSHIFT], 1);
    }
    __syncthreads();
    if (t < NBUCK) {
        int c = hist[t];
        rbase[t] = c ? atomicAdd(&gcur[t], c) : 0;
    }
    __syncthreads();
    if (t < NBUCK) hist[t] = 0;
    __syncthreads();
    for (int i = base + t; i < end; i += 256) {
        int s, d;
        if (i < N_EDGES) { s = ei[i]; d = ei[N_EDGES + i]; } else { s = d = i - N_EDGES; }
        int b = d >> BSHIFT;
        int pos = rbase[b] + atomicAdd(&hist[b], 1);
        ebuf[pos] = make_uint2((uintT)s, (uintT)d);
    }
}

__global__ __launch_bounds__(256) void csr_local(const uint2* __restrict__ ebuf,
                                                 const int* __restrict__ bbase,
                                                 int* __restrict__ rowptr,
                                                 int* __restrict__ ssrc) {
    __shared__ int cnt[512];
    __shared__ int cur[512];
    __shared__ int wsum[4];
    int b = blockIdx.x;
    int t = threadIdx.x;
    int node0 = b << BSHIFT;
    int nb = min(512, N_NODES - node0);
    int beg = bbase[b], end = bbase[b + 1];
    cnt[t] = 0; cnt[t + 256] = 0;
    __syncthreads();
    for (int i = beg + t; i < end; i += 256)
        atomicAdd(&cnt[ebuf[i].y & 511], 1);
    __syncthreads();
    int v0 = cnt[2 * t], v1 = cnt[2 * t + 1];
    int s = v0 + v1;
    int lane = t & 63, w = t >> 6;
    int x = s;
#pragma unroll
    for (int off = 1; off < 64; off <<= 1) { int y = __shfl_up(x, off); if (lane >= off) x += y; }
    if (lane == 63) wsum[w] = x;
    __syncthreads();
    if (t == 0) { int run = 0; for (int k = 0; k < 4; ++k) { int tmp = wsum[k]; wsum[k] = run; run += tmp; } }
    __syncthreads();
    int excl = wsum[w] + x - s;
    cnt[2 * t] = excl; cnt[2 * t + 1] = excl + v0;
    cur[2 * t] = excl; cur[2 * t + 1] = excl + v0;
    if (2 * t < nb)     rowptr[node0 + 2 * t]     = beg + excl;
    if (2 * t + 1 < nb) rowptr[node0 + 2 * t + 1] = beg + excl + v0;
    __syncthreads();
    for (int i = beg + t; i < end; i += 256) {
        uint2 e = ebuf[i];
        int pos = beg + atomicAdd(&cur[e.y & 511], 1);
        ssrc[pos] = (int)e.x;
    }
}

// ---------- fused per-node GAT aggregate ----------
__device__ __forceinline__ float lrelu(float v) { return v > 0.f ? v : SLOPE * v; }

#define WPB 4   // waves (nodes) per block
__global__ __launch_bounds__(256) void gat_gather(
    const int* __restrict__ rowptr, const int* __restrict__ ssrc,
    const float* __restrict__ asrc, const float* __restrict__ adst,
    const ushortT* __restrict__ hpb, const float* __restrict__ bias,
    ushortT* __restrict__ foutB)
{
    __shared__ float s_exp[WPB][64][4];
    __shared__ int   s_src[WPB][64];
    __shared__ float s_m[WPB][4];
    int w = threadIdx.x >> 6;
    int lane = threadIdx.x & 63;
    int node = blockIdx.x * WPB + w;
    if (node >= N_NODES) return;
    int beg = rowptr[node];
    int deg = rowptr[node + 1] - beg;
    float4 ad = *(const float4*)(adst + (size_t)node * 4);
    int g = lane >> 4;       // lane's head / reduce group
    int i0 = lane & 15;
    float acc0 = 0.f, acc1 = 0.f;
    float zinv;
    const ushortT* hrow = hpb + lane * 2;

    if (deg <= 64) {
        // ---- fast path: one edge pass, logits cached in LDS ----
        float4 lg = make_float4(-1e30f, -1e30f, -1e30f, -1e30f);
        if (lane < deg) {
            int s = ssrc[beg + lane];
            float4 a = *(const float4*)(asrc + (size_t)s * 4);
            lg.x = lrelu(a.x + ad.x);
            lg.y = lrelu(a.y + ad.y);
            lg.z = lrelu(a.z + ad.z);
            lg.w = lrelu(a.w + ad.w);
            s_src[w][lane] = s * HC;   // pre-scaled element offset
        }
        *(float4*)&s_exp[w][lane][0] = lg;
        asm volatile("s_waitcnt lgkmcnt(0)" ::: "memory");
        // transpose-reduce max: group g reduces channel g over 64 edges
        float mg =            s_exp[w][i0][g];
        mg = fmaxf(mg, s_exp[w][i0 + 16][g]);
        mg = fmaxf(mg, s_exp[w][i0 + 32][g]);
        mg = fmaxf(mg, s_exp[w][i0 + 48][g]);
#pragma unroll
        for (int off = 1; off < 16; off <<= 1) mg = fmaxf(mg, __shfl_xor(mg, off));
        if (i0 == 0) s_m[w][g] = mg;
        asm volatile("s_waitcnt lgkmcnt(0)" ::: "memory");
        float4 m = *(float4*)&s_m[w][0];
        // exp (inactive lanes: lg=-1e30 -> ex=0)
        float4 ex;
        ex.x = __expf(lg.x - m.x);
        ex.y = __expf(lg.y - m.y);
        ex.z = __expf(lg.z - m.z);
        ex.w = __expf(lg.w - m.w);
        *(float4*)&s_exp[w][lane][0] = ex;
        asm volatile("s_waitcnt lgkmcnt(0)" ::: "memory");
        // transpose-reduce z for own head g (group g == head g owner)
        float zg =        s_exp[w][i0][g];
        zg +=             s_exp[w][i0 + 16][g];
        zg +=             s_exp[w][i0 + 32][g];
        zg +=             s_exp[w][i0 + 48][g];
#pragma unroll
        for (int off = 1; off < 16; off <<= 1) zg += __shfl_xor(zg, off);
        zinv = 1.f / zg;
        // ---- weighted gather ----
#pragma unroll 4
        for (int i = 0; i < deg; ++i) {
            float e = s_exp[w][i][g];
            int off = s_src[w][i];
            uintT u = *(const uintT*)(hrow + off);
            float h0 = __uint_as_float(u << 16);
            float h1 = __uint_as_float(u & 0xffff0000u);
            acc0 = fmaf(h0, e, acc0);
            acc1 = fmaf(h1, e, acc1);
        }
    } else {
        // ---- general path (deg > 64): two-pass ----
        float4 m = make_float4(-1e30f, -1e30f, -1e30f, -1e30f);
        for (int i = lane; i < deg; i += 64) {
            int s = ssrc[beg + i];
            float4 a = *(const float4*)(asrc + (size_t)s * 4);
            m.x = fmaxf(m.x, lrelu(a.x + ad.x));
            m.y = fmaxf(m.y, lrelu(a.y + ad.y));
            m.z = fmaxf(m.z, lrelu(a.z + ad.z));
            m.w = fmaxf(m.w, lrelu(a.w + ad.w));
        }
#pragma unroll
        for (int off = 1; off < 64; off <<= 1) {
            m.x = fmaxf(m.x, __shfl_xor(m.x, off));
            m.y = fmaxf(m.y, __shfl_xor(m.y, off));
            m.z = fmaxf(m.z, __shfl_xor(m.z, off));
            m.w = fmaxf(m.w, __shfl_xor(m.w, off));
        }
        float4 zp = make_float4(0.f, 0.f, 0.f, 0.f);
        for (int c0 = 0; c0 < deg; c0 += 64) {
            int n_ch = min(64, deg - c0);
            if (lane < n_ch) {
                int s = ssrc[beg + c0 + lane];
                float4 a = *(const float4*)(asrc + (size_t)s * 4);
                float4 ex;
                ex.x = __expf(lrelu(a.x + ad.x) - m.x);
                ex.y = __expf(lrelu(a.y + ad.y) - m.y);
                ex.z = __expf(lrelu(a.z + ad.z) - m.z);
                ex.w = __expf(lrelu(a.w + ad.w) - m.w);
                *(float4*)&s_exp[w][lane][0] = ex;
                s_src[w][lane] = s * HC;
                zp.x += ex.x; zp.y += ex.y; zp.z += ex.z; zp.w += ex.w;
            }
            asm volatile("s_waitcnt lgkmcnt(0)" ::: "memory");
#pragma unroll 4
            for (int i = 0; i < n_ch; ++i) {
                float e = s_exp[w][i][g];
                int off = s_src[w][i];
                uintT u = *(const uintT*)(hrow + off);
                float h0 = __uint_as_float(u << 16);
                float h1 = __uint_as_float(u & 0xffff0000u);
                acc0 = fmaf(h0, e, acc0);
                acc1 = fmaf(h1, e, acc1);
            }
        }
#pragma unroll
        for (int off = 1; off < 64; off <<= 1) {
            zp.x += __shfl_xor(zp.x, off);
            zp.y += __shfl_xor(zp.y, off);
            zp.z += __shfl_xor(zp.z, off);
            zp.w += __shfl_xor(zp.w, off);
        }
        float zh = (g == 0) ? zp.x : (g == 1) ? zp.y : (g == 2) ? zp.z : zp.w;
        zinv = 1.f / zh;
    }

    float b0 = bias[lane * 2], b1 = bias[lane * 2 + 1];
    float v0 = acc0 * zinv + b0; v0 = v0 > 0.f ? v0 : __expf(v0) - 1.f;
    float v1 = acc1 * zinv + b1; v1 = v1 > 0.f ? v1 : __expf(v1) - 1.f;
    *(uintT*)(foutB + (size_t)node * HC + lane * 2) =
        (uintT)f2bu(v0) | ((uintT)f2bu(v1) << 16);
}

extern "C" void kernel_launch(void* const* d_in, const int* in_sizes, int n_in,
                              void* d_out, int out_size, void* d_ws, size_t ws_size,
                              hipStream_t stream) {
    const float* x      = (const float*)d_in[0];
    const int*   ei     = (const int*)d_in[1];
    const float* w_in   = (const float*)d_in[2];
    const float* Ws     = (const float*)d_in[3];
    const float* atts   = (const float*)d_in[4];
    const float* biases = (const float*)d_in[5];
    const float* w_out  = (const float*)d_in[6];
    float* out = (float*)d_out;

    // workspace partition
    char* wp = (char*)d_ws;
    ushortT* hb0 = (ushortT*)wp; wp += (size_t)N_NODES * HC * 2;   // bf16 h / final gat out
    ushortT* hb1 = (ushortT*)wp; wp += (size_t)N_NODES * HC * 2;   // bf16 gat_l0 out
    ushortT* hpb = (ushortT*)wp; wp += (size_t)N_NODES * HC * 2;   // bf16 hp
    float* asrc  = (float*)wp;   wp += (size_t)N_NODES * HEADS * 4;
    float* adst  = (float*)wp;   wp += (size_t)N_NODES * HEADS * 4;
    int* rowptr  = (int*)wp;     wp += (size_t)(N_NODES + 4) * 4;
    int* ssrc    = (int*)wp;     wp += (size_t)EE * 4;
    uint2* ebuf  = (uint2*)wp;   wp += (size_t)EE * 8;
    int* bcnt    = (int*)wp;     wp += (size_t)(NBUCK + 4) * 4;
    int* bbase   = (int*)wp;     wp += (size_t)(NBUCK + 4) * 4;
    int* gcur    = (int*)wp;     wp += (size_t)(NBUCK + 4) * 4;
    ushortT* w_inT = (ushortT*)wp; wp += (size_t)HC * F_IN * 2;
    ushortT* WsT   = (ushortT*)wp; wp += (size_t)LAYERS * HC * HC * 2;
    ushortT* woutT = (ushortT*)wp; wp += (size_t)48 * HC * 2;

    // ---- CSR build: two-level bucket sort ----
    hipMemsetAsync(bcnt, 0, (size_t)NBUCK * 4, stream);
    bucket_count<<<NBLK_E, 256, 0, stream>>>(ei, bcnt);
    bucket_scan<<<1, 64, 0, stream>>>(bcnt, bbase, gcur, rowptr);
    bucket_scatter<<<NBLK_E, 256, 0, stream>>>(ei, gcur, ebuf);
    csr_local<<<NBUCK, 256, 0, stream>>>(ebuf, bbase, rowptr, ssrc);

    // ---- weight convert+transpose ----
    wconv<<<(F_IN * HC + 255) / 256, 256, 0, stream>>>(w_in, w_inT, F_IN);
    wconv<<<(HC * HC + 255) / 256, 256, 0, stream>>>(Ws, WsT, HC);
    wconv<<<(HC * HC + 255) / 256, 256, 0, stream>>>(Ws + (size_t)HC * HC, WsT + (size_t)HC * HC, HC);
    wconv_cls<<<(48 * HC + 255) / 256, 256, 0, stream>>>(w_out, woutT);

    int gblk = (N_NODES + 63) / 64;
    // h = x @ w_in  -> bf16 only
    gemm_mfma<true><<<gblk, 256, 0, stream>>>(x, w_inT, (float*)nullptr, hb0, N_NODES, F_IN);

    const ushortT* hin_b = hb0;
    ushortT* gout[LAYERS] = { hb1, hb0 };
    for (int l = 0; l < LAYERS; ++l) {
        gemm_mfma<false><<<gblk, 256, 0, stream>>>(hin_b, WsT + (size_t)l * HC * HC,
                                                   (float*)nullptr, hpb, N_NODES, HC);
        node_alpha<<<(N_NODES * HEADS + 255) / 256, 256, 0, stream>>>(
            hpb, atts + (size_t)l * HEADS * 2 * HID, asrc, adst);
        gat_gather<<<(N_NODES + WPB - 1) / WPB, 64 * WPB, 0, stream>>>(
            rowptr, ssrc, asrc, adst, hpb, biases + (size_t)l * HC, gout[l]);
        hin_b = gout[l];
    }

    cls_mfma<<<gblk, 256, 0, stream>>>(hb0, woutT, out, N_NODES);
}